// Round 9
// baseline (401.781 us; speedup 1.0000x reference)
//
#include <hip/hip_runtime.h>

#define N_NODES 50000
#define N_EDGES 800000
#define HEADS 4
#define NUM_GRAPHS 8

// ============ CSR build ============
__global__ __launch_bounds__(256) void hist_kernel(const int* __restrict__ dst,
                                                   int* __restrict__ deg) {
  int e = blockIdx.x * blockDim.x + threadIdx.x;
  if (e < N_EDGES) atomicAdd(&deg[dst[e]], 1);
}

// Wave-aggregated bump allocation: rowstart[i] = arbitrary contiguous segment
// of length deg[i]. Cross-node order is irrelevant for correctness.
__global__ __launch_bounds__(256) void alloc_kernel(const int* __restrict__ deg,
                                                    int* __restrict__ gctr,
                                                    int* __restrict__ rowstart,
                                                    int* __restrict__ cursor) {
  int i = blockIdx.x * blockDim.x + threadIdx.x;
  int lane = threadIdx.x & 63;
  int d = (i < N_NODES) ? deg[i] : 0;
  int pre = d;
#pragma unroll
  for (int off = 1; off < 64; off <<= 1) {
    int v = __shfl_up(pre, off, 64);
    if (lane >= off) pre += v;
  }
  int total = __shfl(pre, 63, 64);
  int base = 0;
  if (lane == 63) base = atomicAdd(gctr, total);
  base = __shfl(base, 63, 64);
  if (i < N_NODES) {
    int start = base + pre - d;
    rowstart[i] = start;
    cursor[i] = start;
  }
}

// src_perm[slot] = src[e]  (the one unavoidable random scatter)
__global__ __launch_bounds__(256) void scatter_kernel(const int* __restrict__ src,
                                                      const int* __restrict__ dst,
                                                      int* __restrict__ cursor,
                                                      int* __restrict__ src_perm) {
  int e = blockIdx.x * blockDim.x + threadIdx.x;
  if (e >= N_EDGES) return;
  int p = atomicAdd(&cursor[dst[e]], 1);
  src_perm[p] = src[e];
}

// ============ fc0: h0 = relu(x@W0+b0) [N,16]; P1[n,h] = h0[n]·u1[:,h] ============
__global__ __launch_bounds__(256) void fc0_kernel(
    const float* __restrict__ x,
    const float* __restrict__ fc0_w, const float* __restrict__ fc0_b,
    const float* __restrict__ u1,
    float* __restrict__ h0, float* __restrict__ P1) {
  __shared__ float sW0[3 * 16];
  __shared__ float sB0[16];
  __shared__ float sU[16 * 4];
  for (int i = threadIdx.x; i < 48; i += blockDim.x) sW0[i] = fc0_w[i];
  for (int i = threadIdx.x; i < 16; i += blockDim.x) sB0[i] = fc0_b[i];
  for (int i = threadIdx.x; i < 64; i += blockDim.x) sU[i] = u1[i];
  __syncthreads();
  int n = blockIdx.x * blockDim.x + threadIdx.x;
  if (n >= N_NODES) return;
  float x0 = x[n * 3 + 0], x1 = x[n * 3 + 1], x2 = x[n * 3 + 2];
  float h[16];
#pragma unroll
  for (int j = 0; j < 16; j++) {
    float v = x0 * sW0[0 * 16 + j] + x1 * sW0[1 * 16 + j] + x2 * sW0[2 * 16 + j] + sB0[j];
    h[j] = fmaxf(v, 0.f);
    h0[(size_t)n * 16 + j] = h[j];
  }
  float p0 = 0.f, p1 = 0.f, p2 = 0.f, p3 = 0.f;
#pragma unroll
  for (int j = 0; j < 16; j++) {
    p0 += h[j] * sU[j * 4 + 0];
    p1 += h[j] * sU[j * 4 + 1];
    p2 += h[j] * sU[j * 4 + 2];
    p3 += h[j] * sU[j * 4 + 3];
  }
  reinterpret_cast<float4*>(P1)[n] = make_float4(p0, p1, p2, p3);
}

// ============ proj2: P2[n,h] = h1[n]·u2[:,h]  (CIN=32) ============
__global__ __launch_bounds__(256) void proj2_kernel(
    const float* __restrict__ h1, const float* __restrict__ u2,
    float* __restrict__ P2) {
  __shared__ float sU[32 * 4];
  for (int i = threadIdx.x; i < 128; i += blockDim.x) sU[i] = u2[i];
  __syncthreads();
  int n = blockIdx.x * blockDim.x + threadIdx.x;
  if (n >= N_NODES) return;
  const float4* hr = reinterpret_cast<const float4*>(h1 + (size_t)n * 32);
  float p0 = 0.f, p1 = 0.f, p2 = 0.f, p3 = 0.f;
#pragma unroll
  for (int j4 = 0; j4 < 8; j4++) {
    float4 a = hr[j4];
#pragma unroll
    for (int k = 0; k < 4; k++) {
      float hv = k == 0 ? a.x : k == 1 ? a.y : k == 2 ? a.z : a.w;
      int j = 4 * j4 + k;
      p0 += hv * sU[j * 4 + 0];
      p1 += hv * sU[j * 4 + 1];
      p2 += hv * sU[j * 4 + 2];
      p3 += hv * sU[j * 4 + 3];
    }
  }
  reinterpret_cast<float4*>(P2)[n] = make_float4(p0, p1, p2, p3);
}

// ============ Q kernel: per-edge softmax computed ONCE per edge ============
// Wave per node; lane l handles CSR slot e0+l. Writes coalesced float4
// q_perm[p]. Works for both layers (depends only on P and c).
__global__ __launch_bounds__(256) void q_kernel(
    const int* __restrict__ rowstart, const int* __restrict__ deg,
    const int* __restrict__ src_perm,
    const float* __restrict__ P, const float* __restrict__ cb,
    float* __restrict__ q_perm) {
  int wid = (blockIdx.x * (blockDim.x >> 6)) + (threadIdx.x >> 6);
  int lane = threadIdx.x & 63;
  if (wid >= N_NODES) return;
  float4 Pd = reinterpret_cast<const float4*>(P)[wid];
  float b0 = cb[0] - Pd.x, b1 = cb[1] - Pd.y, b2 = cb[2] - Pd.z, b3 = cb[3] - Pd.w;
  int e0 = rowstart[wid];
  int d = deg[wid];
  for (int l = lane; l < d; l += 64) {
    int p = e0 + l;
    int s = src_perm[p];
    float4 Ps = reinterpret_cast<const float4*>(P)[s];
    float l0 = Ps.x + b0, l1 = Ps.y + b1, l2 = Ps.z + b2, l3 = Ps.w + b3;
    float m = fmaxf(fmaxf(l0, l1), fmaxf(l2, l3));
    float e0v = __expf(l0 - m), e1v = __expf(l1 - m), e2v = __expf(l2 - m), e3v = __expf(l3 - m);
    float inv = 1.f / (e0v + e1v + e2v + e3v);
    reinterpret_cast<float4*>(q_perm)[p] =
        make_float4(e0v * inv, e1v * inv, e2v * inv, e3v * inv);
  }
}

// ============ AGG layer 1 (CIN=16): A[n,hh*16+j] = sum q[e,hh]*h0[s,j] ============
// Wave per node; per edge: sequential src/q loads + one h0 gather + 1 FMA.
__global__ __launch_bounds__(256) void agg1_kernel(
    const int* __restrict__ rowstart, const int* __restrict__ deg,
    const int* __restrict__ src_perm, const float* __restrict__ q_perm,
    const float* __restrict__ h0,
    float* __restrict__ A) {
  int wave = threadIdx.x >> 6;
  int lane = threadIdx.x & 63;
  int hh = lane >> 4;
  int j = lane & 15;
  int node = blockIdx.x * 4 + wave;
  if (node >= N_NODES) return;
  int e0 = rowstart[node];
  int e1 = e0 + deg[node];
  float acc = 0.f;
  int p = e0;
  for (; p + 2 <= e1; p += 2) {
    int s0 = src_perm[p];
    int s1 = src_perm[p + 1];
    float4 q0 = reinterpret_cast<const float4*>(q_perm)[p];
    float4 q1 = reinterpret_cast<const float4*>(q_perm)[p + 1];
    float f0 = h0[(size_t)s0 * 16 + j];
    float f1 = h0[(size_t)s1 * 16 + j];
    float qa = hh == 0 ? q0.x : hh == 1 ? q0.y : hh == 2 ? q0.z : q0.w;
    float qb = hh == 0 ? q1.x : hh == 1 ? q1.y : hh == 2 ? q1.z : q1.w;
    acc += qa * f0 + qb * f1;
  }
  for (; p < e1; p++) {
    int s = src_perm[p];
    float4 q = reinterpret_cast<const float4*>(q_perm)[p];
    float f = h0[(size_t)s * 16 + j];
    float qa = hh == 0 ? q.x : hh == 1 ? q.y : hh == 2 ? q.z : q.w;
    acc += qa * f;
  }
  A[(size_t)node * 64 + lane] = acc;  // A[node][hh*16+j]
}

// ============ AGG layer 2 (CIN=32): lane = hp*32+j covers heads {hp, hp+2} ============
__global__ __launch_bounds__(256) void agg2_kernel(
    const int* __restrict__ rowstart, const int* __restrict__ deg,
    const int* __restrict__ src_perm, const float* __restrict__ q_perm,
    const float* __restrict__ h1,
    float* __restrict__ A) {
  int wave = threadIdx.x >> 6;
  int lane = threadIdx.x & 63;
  int hp = lane >> 5;
  int j = lane & 31;
  int node = blockIdx.x * 4 + wave;
  if (node >= N_NODES) return;
  int e0 = rowstart[node];
  int e1 = e0 + deg[node];
  float acca = 0.f, accb = 0.f;
  int p = e0;
  for (; p + 2 <= e1; p += 2) {
    int s0 = src_perm[p];
    int s1 = src_perm[p + 1];
    float4 q0 = reinterpret_cast<const float4*>(q_perm)[p];
    float4 q1 = reinterpret_cast<const float4*>(q_perm)[p + 1];
    float f0 = h1[(size_t)s0 * 32 + j];
    float f1 = h1[(size_t)s1 * 32 + j];
    float qa0 = hp == 0 ? q0.x : q0.y;
    float qb0 = hp == 0 ? q0.z : q0.w;
    float qa1 = hp == 0 ? q1.x : q1.y;
    float qb1 = hp == 0 ? q1.z : q1.w;
    acca += qa0 * f0 + qa1 * f1;
    accb += qb0 * f0 + qb1 * f1;
  }
  for (; p < e1; p++) {
    int s = src_perm[p];
    float4 q = reinterpret_cast<const float4*>(q_perm)[p];
    float f = h1[(size_t)s * 32 + j];
    float qa = hp == 0 ? q.x : q.y;
    float qb = hp == 0 ? q.z : q.w;
    acca += qa * f;
    accb += qb * f;
  }
  A[(size_t)node * 128 + hp * 32 + j] = acca;        // head hp
  A[(size_t)node * 128 + (hp + 2) * 32 + j] = accb;  // head hp+2
}

// ============ GEMM1: h1 = relu((A1 @ B1)/deg + b1), A1:[N,64], B1:[64,32] ============
__global__ __launch_bounds__(256) void gemm1_kernel(
    const int* __restrict__ deg, const float* __restrict__ A,
    const float* __restrict__ w1, const float* __restrict__ b1,
    float* __restrict__ h1) {
  __shared__ float sB[64 * 32];  // 8 KB; sB[k][c] = B1[k][c]
  for (int i = threadIdx.x; i < 64 * 32; i += 256) {
    int hj = i / 32, c = i % 32;
    sB[i] = w1[(hj % 16) * 128 + (hj / 16) * 32 + c];
  }
  __syncthreads();
  const float4* sB4 = reinterpret_cast<const float4*>(sB);
  int c4 = threadIdx.x & 7;       // 8 float4 slots = 32 channels
  int g = threadIdx.x >> 3;       // 32 pairs x 2 nodes = 64 nodes/block
  int n0 = blockIdx.x * 64 + g * 2;
  int n1 = n0 + 1;
  int na = min(n0, N_NODES - 1);
  int nb = min(n1, N_NODES - 1);
  const float4* A0 = reinterpret_cast<const float4*>(A + (size_t)na * 64);
  const float4* A1 = reinterpret_cast<const float4*>(A + (size_t)nb * 64);
  float4 bc = reinterpret_cast<const float4*>(b1)[c4];
  float4 acc0 = {0, 0, 0, 0}, acc1 = {0, 0, 0, 0};
#pragma unroll 2
  for (int k4 = 0; k4 < 16; k4++) {
    float4 a0 = A0[k4];
    float4 a1 = A1[k4];
    float4 w0 = sB4[(4 * k4 + 0) * 8 + c4];
    float4 wv1 = sB4[(4 * k4 + 1) * 8 + c4];
    float4 w2v = sB4[(4 * k4 + 2) * 8 + c4];
    float4 w3 = sB4[(4 * k4 + 3) * 8 + c4];
    acc0.x += a0.x * w0.x + a0.y * wv1.x + a0.z * w2v.x + a0.w * w3.x;
    acc0.y += a0.x * w0.y + a0.y * wv1.y + a0.z * w2v.y + a0.w * w3.y;
    acc0.z += a0.x * w0.z + a0.y * wv1.z + a0.z * w2v.z + a0.w * w3.z;
    acc0.w += a0.x * w0.w + a0.y * wv1.w + a0.z * w2v.w + a0.w * w3.w;
    acc1.x += a1.x * w0.x + a1.y * wv1.x + a1.z * w2v.x + a1.w * w3.x;
    acc1.y += a1.x * w0.y + a1.y * wv1.y + a1.z * w2v.y + a1.w * w3.y;
    acc1.z += a1.x * w0.z + a1.y * wv1.z + a1.z * w2v.z + a1.w * w3.z;
    acc1.w += a1.x * w0.w + a1.y * wv1.w + a1.z * w2v.w + a1.w * w3.w;
  }
  if (n0 < N_NODES) {
    float inv = 1.f / fmaxf((float)deg[n0], 1.f);
    float4 o = {fmaxf(acc0.x * inv + bc.x, 0.f), fmaxf(acc0.y * inv + bc.y, 0.f),
                fmaxf(acc0.z * inv + bc.z, 0.f), fmaxf(acc0.w * inv + bc.w, 0.f)};
    reinterpret_cast<float4*>(h1 + (size_t)n0 * 32)[c4] = o;
  }
  if (n1 < N_NODES) {
    float inv = 1.f / fmaxf((float)deg[n1], 1.f);
    float4 o = {fmaxf(acc1.x * inv + bc.x, 0.f), fmaxf(acc1.y * inv + bc.y, 0.f),
                fmaxf(acc1.z * inv + bc.z, 0.f), fmaxf(acc1.w * inv + bc.w, 0.f)};
    reinterpret_cast<float4*>(h1 + (size_t)n1 * 32)[c4] = o;
  }
}

// ============ GEMM2: h2 = relu((A2 @ B2)/deg + b2), A2:[N,128], B2:[128,64] ============
__global__ __launch_bounds__(256) void gemm2_kernel(
    const int* __restrict__ deg, const float* __restrict__ A,
    const float* __restrict__ w2, const float* __restrict__ b2,
    float* __restrict__ h2) {
  __shared__ float sB[128 * 64];  // 32 KB; sB[k][c] = B2[k][c]
  for (int i = threadIdx.x; i < 128 * 64; i += 256) {
    int hj = i / 64, c = i % 64;
    sB[i] = w2[(hj % 32) * 256 + (hj / 32) * 64 + c];
  }
  __syncthreads();
  const float4* sB4 = reinterpret_cast<const float4*>(sB);
  int c4 = threadIdx.x & 15;      // 16 float4 slots = 64 channels
  int g = threadIdx.x >> 4;       // 16 pairs x 2 nodes = 32 nodes/block
  int n0 = blockIdx.x * 32 + g * 2;
  int n1 = n0 + 1;
  int na = min(n0, N_NODES - 1);
  int nb = min(n1, N_NODES - 1);
  const float4* A0 = reinterpret_cast<const float4*>(A + (size_t)na * 128);
  const float4* A1 = reinterpret_cast<const float4*>(A + (size_t)nb * 128);
  float4 bc = reinterpret_cast<const float4*>(b2)[c4];
  float4 acc0 = {0, 0, 0, 0}, acc1 = {0, 0, 0, 0};
#pragma unroll 2
  for (int k4 = 0; k4 < 32; k4++) {
    float4 a0 = A0[k4];
    float4 a1 = A1[k4];
    float4 w0 = sB4[(4 * k4 + 0) * 16 + c4];
    float4 wv1 = sB4[(4 * k4 + 1) * 16 + c4];
    float4 w2v = sB4[(4 * k4 + 2) * 16 + c4];
    float4 w3 = sB4[(4 * k4 + 3) * 16 + c4];
    acc0.x += a0.x * w0.x + a0.y * wv1.x + a0.z * w2v.x + a0.w * w3.x;
    acc0.y += a0.x * w0.y + a0.y * wv1.y + a0.z * w2v.y + a0.w * w3.y;
    acc0.z += a0.x * w0.z + a0.y * wv1.z + a0.z * w2v.z + a0.w * w3.z;
    acc0.w += a0.x * w0.w + a0.y * wv1.w + a0.z * w2v.w + a0.w * w3.w;
    acc1.x += a1.x * w0.x + a1.y * wv1.x + a1.z * w2v.x + a1.w * w3.x;
    acc1.y += a1.x * w0.y + a1.y * wv1.y + a1.z * w2v.y + a1.w * w3.y;
    acc1.z += a1.x * w0.z + a1.y * wv1.z + a1.z * w2v.z + a1.w * w3.z;
    acc1.w += a1.x * w0.w + a1.y * wv1.w + a1.z * w2v.w + a1.w * w3.w;
  }
  if (n0 < N_NODES) {
    float inv = 1.f / fmaxf((float)deg[n0], 1.f);
    float4 o = {fmaxf(acc0.x * inv + bc.x, 0.f), fmaxf(acc0.y * inv + bc.y, 0.f),
                fmaxf(acc0.z * inv + bc.z, 0.f), fmaxf(acc0.w * inv + bc.w, 0.f)};
    reinterpret_cast<float4*>(h2 + (size_t)n0 * 64)[c4] = o;
  }
  if (n1 < N_NODES) {
    float inv = 1.f / fmaxf((float)deg[n1], 1.f);
    float4 o = {fmaxf(acc1.x * inv + bc.x, 0.f), fmaxf(acc1.y * inv + bc.y, 0.f),
                fmaxf(acc1.z * inv + bc.z, 0.f), fmaxf(acc1.w * inv + bc.w, 0.f)};
    reinterpret_cast<float4*>(h2 + (size_t)n1 * 64)[c4] = o;
  }
}

// ============ Pool: per-graph mean of h2 (batch sorted) ============
#define POOL_CHUNK 64
__global__ __launch_bounds__(256) void pool_kernel(
    const float* __restrict__ h2, const int* __restrict__ batch,
    float* __restrict__ gsum, float* __restrict__ gcnt) {
  int grp = threadIdx.x / 64;
  int c = threadIdx.x % 64;
  int n0 = (blockIdx.x * 4 + grp) * POOL_CHUNK;
  int n1 = min(n0 + POOL_CHUNK, N_NODES);
  if (n0 >= N_NODES) return;
  float acc = 0.f;
  float cacc = 0.f;
  int curg = batch[n0];
  for (int n = n0; n < n1; n++) {
    int g = batch[n];
    float v = h2[(size_t)n * 64 + c];
    if (g != curg) {
      atomicAdd(&gsum[curg * 64 + c], acc);
      if (c == 0) atomicAdd(&gcnt[curg], cacc);
      acc = 0.f;
      cacc = 0.f;
      curg = g;
    }
    acc += v;
    cacc += 1.f;
  }
  atomicAdd(&gsum[curg * 64 + c], acc);
  if (c == 0) atomicAdd(&gcnt[curg], cacc);
}

// ============ Head: out = (gsum/gcnt) @ fc1_w + fc1_b ============
__global__ __launch_bounds__(128) void head_kernel(
    const float* __restrict__ gsum, const float* __restrict__ gcnt,
    const float* __restrict__ fc1_w, const float* __restrict__ fc1_b,
    float* __restrict__ out) {
  int t = threadIdx.x;
  if (t >= NUM_GRAPHS * 10) return;
  int g = t / 10, k = t % 10;
  float inv = 1.f / fmaxf(gcnt[g], 1.f);
  float s = fc1_b[k];
#pragma unroll
  for (int c = 0; c < 64; c++) s += gsum[g * 64 + c] * inv * fc1_w[c * 10 + k];
  out[g * 10 + k] = s;
}

extern "C" void kernel_launch(void* const* d_in, const int* in_sizes, int n_in,
                              void* d_out, int out_size, void* d_ws, size_t ws_size,
                              hipStream_t stream) {
  const float* x = (const float*)d_in[0];
  const int* edge_index = (const int*)d_in[1];
  const int* batch = (const int*)d_in[2];
  const float* fc0_w = (const float*)d_in[3];
  const float* fc0_b = (const float*)d_in[4];
  const float* u1 = (const float*)d_in[5];
  const float* c1 = (const float*)d_in[6];
  const float* w1 = (const float*)d_in[7];
  const float* b1 = (const float*)d_in[8];
  const float* u2 = (const float*)d_in[9];
  const float* c2 = (const float*)d_in[10];
  const float* w2 = (const float*)d_in[11];
  const float* b2 = (const float*)d_in[12];
  const float* fc1_w = (const float*)d_in[13];
  const float* fc1_b = (const float*)d_in[14];
  float* out = (float*)d_out;

  const int* src = edge_index;            // x_j
  const int* dst = edge_index + N_EDGES;  // x_i

  // ---- workspace layout (4-byte words) ----
  char* wsb = (char*)d_ws;
  int* deg = (int*)wsb;                          // N    [memset with gctr]
  int* gctr = deg + N_NODES;                     // 1
  int* rowstart = (int*)wsb + 50004;             // N
  int* cursor = rowstart + N_NODES;              // N
  int* src_perm = cursor + N_NODES;              // E
  // words: 50004 + 2N + E = 950004
  float* q_perm = (float*)wsb + 950004;          // E*4
  float* h0 = q_perm + (size_t)N_EDGES * 4;      // N*16
  float* h1 = h0 + (size_t)N_NODES * 16;         // N*32
  float* h2 = h1 + (size_t)N_NODES * 32;         // N*64
  float* A = h2 + (size_t)N_NODES * 64;          // N*128 (layers 1 & 2)
  float* P1 = A + (size_t)N_NODES * 128;         // N*4
  float* P2 = P1 + (size_t)N_NODES * 4;          // N*4
  float* gsum = P2 + (size_t)N_NODES * 4;        // 8*64
  float* gcnt = gsum + NUM_GRAPHS * 64;          // 8

  hipMemsetAsync(deg, 0, (N_NODES + 1) * sizeof(int), stream);  // deg + gctr
  hipMemsetAsync(gsum, 0, (NUM_GRAPHS * 64 + NUM_GRAPHS) * sizeof(float), stream);

  int nblk = (N_NODES + 255) / 256;
  int eblk = (N_EDGES + 255) / 256;
  int wblk = (N_NODES + 3) / 4;  // wave-per-node kernels, 4 waves/block

  // CSR build
  hist_kernel<<<eblk, 256, 0, stream>>>(dst, deg);
  alloc_kernel<<<nblk, 256, 0, stream>>>(deg, gctr, rowstart, cursor);
  scatter_kernel<<<eblk, 256, 0, stream>>>(src, dst, cursor, src_perm);

  // Layer 0 (+ P1 projection)
  fc0_kernel<<<nblk, 256, 0, stream>>>(x, fc0_w, fc0_b, u1, h0, P1);

  // FeaStConv 1: q (once per edge) -> agg -> GEMM
  q_kernel<<<wblk, 256, 0, stream>>>(rowstart, deg, src_perm, P1, c1, q_perm);
  agg1_kernel<<<wblk, 256, 0, stream>>>(rowstart, deg, src_perm, q_perm, h0, A);
  gemm1_kernel<<<(N_NODES + 63) / 64, 256, 0, stream>>>(deg, A, w1, b1, h1);

  // FeaStConv 2
  proj2_kernel<<<nblk, 256, 0, stream>>>(h1, u2, P2);
  q_kernel<<<wblk, 256, 0, stream>>>(rowstart, deg, src_perm, P2, c2, q_perm);
  agg2_kernel<<<wblk, 256, 0, stream>>>(rowstart, deg, src_perm, q_perm, h1, A);
  gemm2_kernel<<<(N_NODES + 31) / 32, 256, 0, stream>>>(deg, A, w2, b2, h2);

  // Pool + head
  int pblk = (N_NODES + POOL_CHUNK * 4 - 1) / (POOL_CHUNK * 4);
  pool_kernel<<<pblk, 256, 0, stream>>>(h2, batch, gsum, gcnt);
  head_kernel<<<1, 128, 0, stream>>>(gsum, gcnt, fc1_w, fc1_b, out);
}

// Round 10
// 301.776 us; speedup vs baseline: 1.3314x; 1.3314x over previous
//
#include <hip/hip_runtime.h>

#define N_NODES 50000
#define N_EDGES 800000
#define HEADS 4
#define NUM_GRAPHS 8

// ============ CSR build ============
// off[e] = arrival index of edge e within its dst node (atomic return value).
__global__ __launch_bounds__(256) void hist_kernel(const int* __restrict__ dst,
                                                   int* __restrict__ deg,
                                                   int* __restrict__ off) {
  int e = blockIdx.x * blockDim.x + threadIdx.x;
  if (e < N_EDGES) off[e] = atomicAdd(&deg[dst[e]], 1);
}

// Wave-aggregated bump allocation: rowstart[i] = arbitrary contiguous segment
// of length deg[i]. Cross-node order is irrelevant for correctness.
__global__ __launch_bounds__(256) void alloc_kernel(const int* __restrict__ deg,
                                                    int* __restrict__ gctr,
                                                    int* __restrict__ rowstart) {
  int i = blockIdx.x * blockDim.x + threadIdx.x;
  int lane = threadIdx.x & 63;
  int d = (i < N_NODES) ? deg[i] : 0;
  int pre = d;
#pragma unroll
  for (int offd = 1; offd < 64; offd <<= 1) {
    int v = __shfl_up(pre, offd, 64);
    if (lane >= offd) pre += v;
  }
  int total = __shfl(pre, 63, 64);
  int base = 0;
  if (lane == 63) base = atomicAdd(gctr, total);
  base = __shfl(base, 63, 64);
  if (i < N_NODES) rowstart[i] = base + pre - d;
}

// src_perm[rowstart[dst]+off] = src  — atomic-free random scatter.
__global__ __launch_bounds__(256) void scatter_kernel(const int* __restrict__ src,
                                                      const int* __restrict__ dst,
                                                      const int* __restrict__ rowstart,
                                                      const int* __restrict__ off,
                                                      int* __restrict__ src_perm) {
  int e = blockIdx.x * blockDim.x + threadIdx.x;
  if (e >= N_EDGES) return;
  int p = rowstart[dst[e]] + off[e];
  src_perm[p] = src[e];
}

// ============ fc0: h0 = relu(x@W0+b0) [N,16]; P1[n,h] = h0[n]·u1[:,h] ============
__global__ __launch_bounds__(256) void fc0_kernel(
    const float* __restrict__ x,
    const float* __restrict__ fc0_w, const float* __restrict__ fc0_b,
    const float* __restrict__ u1,
    float* __restrict__ h0, float* __restrict__ P1) {
  __shared__ float sW0[3 * 16];
  __shared__ float sB0[16];
  __shared__ float sU[16 * 4];
  for (int i = threadIdx.x; i < 48; i += blockDim.x) sW0[i] = fc0_w[i];
  for (int i = threadIdx.x; i < 16; i += blockDim.x) sB0[i] = fc0_b[i];
  for (int i = threadIdx.x; i < 64; i += blockDim.x) sU[i] = u1[i];
  __syncthreads();
  int n = blockIdx.x * blockDim.x + threadIdx.x;
  if (n >= N_NODES) return;
  float x0 = x[n * 3 + 0], x1 = x[n * 3 + 1], x2 = x[n * 3 + 2];
  float h[16];
#pragma unroll
  for (int j = 0; j < 16; j++) {
    float v = x0 * sW0[0 * 16 + j] + x1 * sW0[1 * 16 + j] + x2 * sW0[2 * 16 + j] + sB0[j];
    h[j] = fmaxf(v, 0.f);
    h0[(size_t)n * 16 + j] = h[j];
  }
  float p0 = 0.f, p1 = 0.f, p2 = 0.f, p3 = 0.f;
#pragma unroll
  for (int j = 0; j < 16; j++) {
    p0 += h[j] * sU[j * 4 + 0];
    p1 += h[j] * sU[j * 4 + 1];
    p2 += h[j] * sU[j * 4 + 2];
    p3 += h[j] * sU[j * 4 + 3];
  }
  reinterpret_cast<float4*>(P1)[n] = make_float4(p0, p1, p2, p3);
}

// ============ proj2: P2[n,h] = h1[n]·u2[:,h]  (CIN=32) ============
__global__ __launch_bounds__(256) void proj2_kernel(
    const float* __restrict__ h1, const float* __restrict__ u2,
    float* __restrict__ P2) {
  __shared__ float sU[32 * 4];
  for (int i = threadIdx.x; i < 128; i += blockDim.x) sU[i] = u2[i];
  __syncthreads();
  int n = blockIdx.x * blockDim.x + threadIdx.x;
  if (n >= N_NODES) return;
  const float4* hr = reinterpret_cast<const float4*>(h1 + (size_t)n * 32);
  float p0 = 0.f, p1 = 0.f, p2 = 0.f, p3 = 0.f;
#pragma unroll
  for (int j4 = 0; j4 < 8; j4++) {
    float4 a = hr[j4];
#pragma unroll
    for (int k = 0; k < 4; k++) {
      float hv = k == 0 ? a.x : k == 1 ? a.y : k == 2 ? a.z : a.w;
      int j = 4 * j4 + k;
      p0 += hv * sU[j * 4 + 0];
      p1 += hv * sU[j * 4 + 1];
      p2 += hv * sU[j * 4 + 2];
      p3 += hv * sU[j * 4 + 3];
    }
  }
  reinterpret_cast<float4*>(P2)[n] = make_float4(p0, p1, p2, p3);
}

// ============ Q kernel: per-edge softmax computed ONCE per edge ============
__global__ __launch_bounds__(256) void q_kernel(
    const int* __restrict__ rowstart, const int* __restrict__ deg,
    const int* __restrict__ src_perm,
    const float* __restrict__ P, const float* __restrict__ cb,
    float* __restrict__ q_perm) {
  int wid = (blockIdx.x * (blockDim.x >> 6)) + (threadIdx.x >> 6);
  int lane = threadIdx.x & 63;
  if (wid >= N_NODES) return;
  float4 Pd = reinterpret_cast<const float4*>(P)[wid];
  float b0 = cb[0] - Pd.x, b1 = cb[1] - Pd.y, b2 = cb[2] - Pd.z, b3 = cb[3] - Pd.w;
  int e0 = rowstart[wid];
  int d = deg[wid];
  for (int l = lane; l < d; l += 64) {
    int p = e0 + l;
    int s = src_perm[p];
    float4 Ps = reinterpret_cast<const float4*>(P)[s];
    float l0 = Ps.x + b0, l1 = Ps.y + b1, l2 = Ps.z + b2, l3 = Ps.w + b3;
    float m = fmaxf(fmaxf(l0, l1), fmaxf(l2, l3));
    float e0v = __expf(l0 - m), e1v = __expf(l1 - m), e2v = __expf(l2 - m), e3v = __expf(l3 - m);
    float inv = 1.f / (e0v + e1v + e2v + e3v);
    reinterpret_cast<float4*>(q_perm)[p] =
        make_float4(e0v * inv, e1v * inv, e2v * inv, e3v * inv);
  }
}

// ============ AGG layer 1 (CIN=16): 4 edges in parallel per wave ============
// lane = g*16+j (g=edge slot, j=channel). Per chunk of 4 edges the wave issues
// one src load (4 ints), one q float4 load, one h0 gather (4 rows, 64 lanes).
// Each lane keeps 4 head-accumulators; cross-edge reduction = 8 shuffles/node.
__global__ __launch_bounds__(256) void agg1_kernel(
    const int* __restrict__ rowstart, const int* __restrict__ deg,
    const int* __restrict__ src_perm, const float* __restrict__ q_perm,
    const float* __restrict__ h0,
    float* __restrict__ A) {
  int wave = threadIdx.x >> 6;
  int lane = threadIdx.x & 63;
  int g = lane >> 4;
  int j = lane & 15;
  int node = blockIdx.x * 4 + wave;
  if (node >= N_NODES) return;
  int e0 = rowstart[node];
  int e1 = e0 + deg[node];
  const float4* q4 = reinterpret_cast<const float4*>(q_perm);
  float a0 = 0.f, a1 = 0.f, a2 = 0.f, a3 = 0.f;
  int p = e0;
  // 16 edges per iteration: 4 independent chunks of 4
  for (; p + 16 <= e1; p += 16) {
    int sA = src_perm[p + 0 + g];
    int sB = src_perm[p + 4 + g];
    int sC = src_perm[p + 8 + g];
    int sD = src_perm[p + 12 + g];
    float4 qA = q4[p + 0 + g];
    float4 qB = q4[p + 4 + g];
    float4 qC = q4[p + 8 + g];
    float4 qD = q4[p + 12 + g];
    float fA = h0[(size_t)sA * 16 + j];
    float fB = h0[(size_t)sB * 16 + j];
    float fC = h0[(size_t)sC * 16 + j];
    float fD = h0[(size_t)sD * 16 + j];
    a0 += qA.x * fA + qB.x * fB + qC.x * fC + qD.x * fD;
    a1 += qA.y * fA + qB.y * fB + qC.y * fC + qD.y * fD;
    a2 += qA.z * fA + qB.z * fB + qC.z * fC + qD.z * fD;
    a3 += qA.w * fA + qB.w * fB + qC.w * fC + qD.w * fD;
  }
  for (; p + 4 <= e1; p += 4) {
    int s = src_perm[p + g];
    float4 q = q4[p + g];
    float f = h0[(size_t)s * 16 + j];
    a0 += q.x * f; a1 += q.y * f; a2 += q.z * f; a3 += q.w * f;
  }
  int rem = e1 - p;
  if (g < rem) {
    int s = src_perm[p + g];
    float4 q = q4[p + g];
    float f = h0[(size_t)s * 16 + j];
    a0 += q.x * f; a1 += q.y * f; a2 += q.z * f; a3 += q.w * f;
  }
  // reduce over the 4 edge-slot groups (lanes j, 16+j, 32+j, 48+j)
  a0 += __shfl_xor(a0, 16, 64); a0 += __shfl_xor(a0, 32, 64);
  a1 += __shfl_xor(a1, 16, 64); a1 += __shfl_xor(a1, 32, 64);
  a2 += __shfl_xor(a2, 16, 64); a2 += __shfl_xor(a2, 32, 64);
  a3 += __shfl_xor(a3, 16, 64); a3 += __shfl_xor(a3, 32, 64);
  float o = (g == 0) ? a0 : (g == 1) ? a1 : (g == 2) ? a2 : a3;
  A[(size_t)node * 64 + lane] = o;  // A[node][g*16+j] = head-g channel-j
}

// ============ AGG layer 2 (CIN=32): 2 edges in parallel per wave ============
// lane = g*32+j (g in {0,1}); 8 edges per main iteration (4 chunks of 2).
__global__ __launch_bounds__(256) void agg2_kernel(
    const int* __restrict__ rowstart, const int* __restrict__ deg,
    const int* __restrict__ src_perm, const float* __restrict__ q_perm,
    const float* __restrict__ h1,
    float* __restrict__ A) {
  int wave = threadIdx.x >> 6;
  int lane = threadIdx.x & 63;
  int g = lane >> 5;
  int j = lane & 31;
  int node = blockIdx.x * 4 + wave;
  if (node >= N_NODES) return;
  int e0 = rowstart[node];
  int e1 = e0 + deg[node];
  const float4* q4 = reinterpret_cast<const float4*>(q_perm);
  float a0 = 0.f, a1 = 0.f, a2 = 0.f, a3 = 0.f;
  int p = e0;
  for (; p + 8 <= e1; p += 8) {
    int sA = src_perm[p + 0 + g];
    int sB = src_perm[p + 2 + g];
    int sC = src_perm[p + 4 + g];
    int sD = src_perm[p + 6 + g];
    float4 qA = q4[p + 0 + g];
    float4 qB = q4[p + 2 + g];
    float4 qC = q4[p + 4 + g];
    float4 qD = q4[p + 6 + g];
    float fA = h1[(size_t)sA * 32 + j];
    float fB = h1[(size_t)sB * 32 + j];
    float fC = h1[(size_t)sC * 32 + j];
    float fD = h1[(size_t)sD * 32 + j];
    a0 += qA.x * fA + qB.x * fB + qC.x * fC + qD.x * fD;
    a1 += qA.y * fA + qB.y * fB + qC.y * fC + qD.y * fD;
    a2 += qA.z * fA + qB.z * fB + qC.z * fC + qD.z * fD;
    a3 += qA.w * fA + qB.w * fB + qC.w * fC + qD.w * fD;
  }
  for (; p + 2 <= e1; p += 2) {
    int s = src_perm[p + g];
    float4 q = q4[p + g];
    float f = h1[(size_t)s * 32 + j];
    a0 += q.x * f; a1 += q.y * f; a2 += q.z * f; a3 += q.w * f;
  }
  int rem = e1 - p;
  if (g < rem) {
    int s = src_perm[p + g];
    float4 q = q4[p + g];
    float f = h1[(size_t)s * 32 + j];
    a0 += q.x * f; a1 += q.y * f; a2 += q.z * f; a3 += q.w * f;
  }
  a0 += __shfl_xor(a0, 32, 64);
  a1 += __shfl_xor(a1, 32, 64);
  a2 += __shfl_xor(a2, 32, 64);
  a3 += __shfl_xor(a3, 32, 64);
  float oa = (g == 0) ? a0 : a1;        // head g
  float ob = (g == 0) ? a2 : a3;        // head g+2
  A[(size_t)node * 128 + lane] = oa;        // [g*32+j]
  A[(size_t)node * 128 + 64 + lane] = ob;   // [(g+2)*32+j]
}

// ============ GEMM1: h1 = relu((A1 @ B1)/deg + b1), A1:[N,64], B1:[64,32] ============
__global__ __launch_bounds__(256) void gemm1_kernel(
    const int* __restrict__ deg, const float* __restrict__ A,
    const float* __restrict__ w1, const float* __restrict__ b1,
    float* __restrict__ h1) {
  __shared__ float sB[64 * 32];  // 8 KB; sB[k][c] = B1[k][c]
  for (int i = threadIdx.x; i < 64 * 32; i += 256) {
    int hj = i / 32, c = i % 32;
    sB[i] = w1[(hj % 16) * 128 + (hj / 16) * 32 + c];
  }
  __syncthreads();
  const float4* sB4 = reinterpret_cast<const float4*>(sB);
  int c4 = threadIdx.x & 7;       // 8 float4 slots = 32 channels
  int g = threadIdx.x >> 3;       // 32 pairs x 2 nodes = 64 nodes/block
  int n0 = blockIdx.x * 64 + g * 2;
  int n1 = n0 + 1;
  int na = min(n0, N_NODES - 1);
  int nb = min(n1, N_NODES - 1);
  const float4* A0 = reinterpret_cast<const float4*>(A + (size_t)na * 64);
  const float4* A1 = reinterpret_cast<const float4*>(A + (size_t)nb * 64);
  float4 bc = reinterpret_cast<const float4*>(b1)[c4];
  float4 acc0 = {0, 0, 0, 0}, acc1 = {0, 0, 0, 0};
#pragma unroll 2
  for (int k4 = 0; k4 < 16; k4++) {
    float4 a0 = A0[k4];
    float4 a1 = A1[k4];
    float4 w0 = sB4[(4 * k4 + 0) * 8 + c4];
    float4 wv1 = sB4[(4 * k4 + 1) * 8 + c4];
    float4 w2v = sB4[(4 * k4 + 2) * 8 + c4];
    float4 w3 = sB4[(4 * k4 + 3) * 8 + c4];
    acc0.x += a0.x * w0.x + a0.y * wv1.x + a0.z * w2v.x + a0.w * w3.x;
    acc0.y += a0.x * w0.y + a0.y * wv1.y + a0.z * w2v.y + a0.w * w3.y;
    acc0.z += a0.x * w0.z + a0.y * wv1.z + a0.z * w2v.z + a0.w * w3.z;
    acc0.w += a0.x * w0.w + a0.y * wv1.w + a0.z * w2v.w + a0.w * w3.w;
    acc1.x += a1.x * w0.x + a1.y * wv1.x + a1.z * w2v.x + a1.w * w3.x;
    acc1.y += a1.x * w0.y + a1.y * wv1.y + a1.z * w2v.y + a1.w * w3.y;
    acc1.z += a1.x * w0.z + a1.y * wv1.z + a1.z * w2v.z + a1.w * w3.z;
    acc1.w += a1.x * w0.w + a1.y * wv1.w + a1.z * w2v.w + a1.w * w3.w;
  }
  if (n0 < N_NODES) {
    float inv = 1.f / fmaxf((float)deg[n0], 1.f);
    float4 o = {fmaxf(acc0.x * inv + bc.x, 0.f), fmaxf(acc0.y * inv + bc.y, 0.f),
                fmaxf(acc0.z * inv + bc.z, 0.f), fmaxf(acc0.w * inv + bc.w, 0.f)};
    reinterpret_cast<float4*>(h1 + (size_t)n0 * 32)[c4] = o;
  }
  if (n1 < N_NODES) {
    float inv = 1.f / fmaxf((float)deg[n1], 1.f);
    float4 o = {fmaxf(acc1.x * inv + bc.x, 0.f), fmaxf(acc1.y * inv + bc.y, 0.f),
                fmaxf(acc1.z * inv + bc.z, 0.f), fmaxf(acc1.w * inv + bc.w, 0.f)};
    reinterpret_cast<float4*>(h1 + (size_t)n1 * 32)[c4] = o;
  }
}

// ============ GEMM2: h2 = relu((A2 @ B2)/deg + b2), A2:[N,128], B2:[128,64] ============
__global__ __launch_bounds__(256) void gemm2_kernel(
    const int* __restrict__ deg, const float* __restrict__ A,
    const float* __restrict__ w2, const float* __restrict__ b2,
    float* __restrict__ h2) {
  __shared__ float sB[128 * 64];  // 32 KB; sB[k][c] = B2[k][c]
  for (int i = threadIdx.x; i < 128 * 64; i += 256) {
    int hj = i / 64, c = i % 64;
    sB[i] = w2[(hj % 32) * 256 + (hj / 32) * 64 + c];
  }
  __syncthreads();
  const float4* sB4 = reinterpret_cast<const float4*>(sB);
  int c4 = threadIdx.x & 15;      // 16 float4 slots = 64 channels
  int g = threadIdx.x >> 4;       // 16 pairs x 2 nodes = 32 nodes/block
  int n0 = blockIdx.x * 32 + g * 2;
  int n1 = n0 + 1;
  int na = min(n0, N_NODES - 1);
  int nb = min(n1, N_NODES - 1);
  const float4* A0 = reinterpret_cast<const float4*>(A + (size_t)na * 128);
  const float4* A1 = reinterpret_cast<const float4*>(A + (size_t)nb * 128);
  float4 bc = reinterpret_cast<const float4*>(b2)[c4];
  float4 acc0 = {0, 0, 0, 0}, acc1 = {0, 0, 0, 0};
#pragma unroll 2
  for (int k4 = 0; k4 < 32; k4++) {
    float4 a0 = A0[k4];
    float4 a1 = A1[k4];
    float4 w0 = sB4[(4 * k4 + 0) * 16 + c4];
    float4 wv1 = sB4[(4 * k4 + 1) * 16 + c4];
    float4 w2v = sB4[(4 * k4 + 2) * 16 + c4];
    float4 w3 = sB4[(4 * k4 + 3) * 16 + c4];
    acc0.x += a0.x * w0.x + a0.y * wv1.x + a0.z * w2v.x + a0.w * w3.x;
    acc0.y += a0.x * w0.y + a0.y * wv1.y + a0.z * w2v.y + a0.w * w3.y;
    acc0.z += a0.x * w0.z + a0.y * wv1.z + a0.z * w2v.z + a0.w * w3.z;
    acc0.w += a0.x * w0.w + a0.y * wv1.w + a0.z * w2v.w + a0.w * w3.w;
    acc1.x += a1.x * w0.x + a1.y * wv1.x + a1.z * w2v.x + a1.w * w3.x;
    acc1.y += a1.x * w0.y + a1.y * wv1.y + a1.z * w2v.y + a1.w * w3.y;
    acc1.z += a1.x * w0.z + a1.y * wv1.z + a1.z * w2v.z + a1.w * w3.z;
    acc1.w += a1.x * w0.w + a1.y * wv1.w + a1.z * w2v.w + a1.w * w3.w;
  }
  if (n0 < N_NODES) {
    float inv = 1.f / fmaxf((float)deg[n0], 1.f);
    float4 o = {fmaxf(acc0.x * inv + bc.x, 0.f), fmaxf(acc0.y * inv + bc.y, 0.f),
                fmaxf(acc0.z * inv + bc.z, 0.f), fmaxf(acc0.w * inv + bc.w, 0.f)};
    reinterpret_cast<float4*>(h2 + (size_t)n0 * 64)[c4] = o;
  }
  if (n1 < N_NODES) {
    float inv = 1.f / fmaxf((float)deg[n1], 1.f);
    float4 o = {fmaxf(acc1.x * inv + bc.x, 0.f), fmaxf(acc1.y * inv + bc.y, 0.f),
                fmaxf(acc1.z * inv + bc.z, 0.f), fmaxf(acc1.w * inv + bc.w, 0.f)};
    reinterpret_cast<float4*>(h2 + (size_t)n1 * 64)[c4] = o;
  }
}

// ============ Pool: per-graph mean of h2 (batch sorted) ============
#define POOL_CHUNK 64
__global__ __launch_bounds__(256) void pool_kernel(
    const float* __restrict__ h2, const int* __restrict__ batch,
    float* __restrict__ gsum, float* __restrict__ gcnt) {
  int grp = threadIdx.x / 64;
  int c = threadIdx.x % 64;
  int n0 = (blockIdx.x * 4 + grp) * POOL_CHUNK;
  int n1 = min(n0 + POOL_CHUNK, N_NODES);
  if (n0 >= N_NODES) return;
  float acc = 0.f;
  float cacc = 0.f;
  int curg = batch[n0];
  for (int n = n0; n < n1; n++) {
    int g = batch[n];
    float v = h2[(size_t)n * 64 + c];
    if (g != curg) {
      atomicAdd(&gsum[curg * 64 + c], acc);
      if (c == 0) atomicAdd(&gcnt[curg], cacc);
      acc = 0.f;
      cacc = 0.f;
      curg = g;
    }
    acc += v;
    cacc += 1.f;
  }
  atomicAdd(&gsum[curg * 64 + c], acc);
  if (c == 0) atomicAdd(&gcnt[curg], cacc);
}

// ============ Head: out = (gsum/gcnt) @ fc1_w + fc1_b ============
__global__ __launch_bounds__(128) void head_kernel(
    const float* __restrict__ gsum, const float* __restrict__ gcnt,
    const float* __restrict__ fc1_w, const float* __restrict__ fc1_b,
    float* __restrict__ out) {
  int t = threadIdx.x;
  if (t >= NUM_GRAPHS * 10) return;
  int g = t / 10, k = t % 10;
  float inv = 1.f / fmaxf(gcnt[g], 1.f);
  float s = fc1_b[k];
#pragma unroll
  for (int c = 0; c < 64; c++) s += gsum[g * 64 + c] * inv * fc1_w[c * 10 + k];
  out[g * 10 + k] = s;
}

extern "C" void kernel_launch(void* const* d_in, const int* in_sizes, int n_in,
                              void* d_out, int out_size, void* d_ws, size_t ws_size,
                              hipStream_t stream) {
  const float* x = (const float*)d_in[0];
  const int* edge_index = (const int*)d_in[1];
  const int* batch = (const int*)d_in[2];
  const float* fc0_w = (const float*)d_in[3];
  const float* fc0_b = (const float*)d_in[4];
  const float* u1 = (const float*)d_in[5];
  const float* c1 = (const float*)d_in[6];
  const float* w1 = (const float*)d_in[7];
  const float* b1 = (const float*)d_in[8];
  const float* u2 = (const float*)d_in[9];
  const float* c2 = (const float*)d_in[10];
  const float* w2 = (const float*)d_in[11];
  const float* b2 = (const float*)d_in[12];
  const float* fc1_w = (const float*)d_in[13];
  const float* fc1_b = (const float*)d_in[14];
  float* out = (float*)d_out;

  const int* src = edge_index;            // x_j
  const int* dst = edge_index + N_EDGES;  // x_i

  // ---- workspace layout (4-byte words) ----
  char* wsb = (char*)d_ws;
  int* deg = (int*)wsb;                          // N    [memset with gctr]
  int* gctr = deg + N_NODES;                     // 1
  int* rowstart = (int*)wsb + 50004;             // N
  int* off = rowstart + N_NODES;                 // E
  int* src_perm = off + N_EDGES;                 // E
  // words: 50004 + N + 2E = 1700004  (multiple of 4 -> 16B aligned)
  float* q_perm = (float*)wsb + 1700004;         // E*4
  float* h0 = q_perm + (size_t)N_EDGES * 4;      // N*16
  float* h1 = h0 + (size_t)N_NODES * 16;         // N*32
  float* h2 = h1 + (size_t)N_NODES * 32;         // N*64
  float* A = h2 + (size_t)N_NODES * 64;          // N*128 (layers 1 & 2)
  float* P1 = A + (size_t)N_NODES * 128;         // N*4
  float* P2 = P1 + (size_t)N_NODES * 4;          // N*4
  float* gsum = P2 + (size_t)N_NODES * 4;        // 8*64
  float* gcnt = gsum + NUM_GRAPHS * 64;          // 8

  hipMemsetAsync(deg, 0, (N_NODES + 1) * sizeof(int), stream);  // deg + gctr
  hipMemsetAsync(gsum, 0, (NUM_GRAPHS * 64 + NUM_GRAPHS) * sizeof(float), stream);

  int nblk = (N_NODES + 255) / 256;
  int eblk = (N_EDGES + 255) / 256;
  int wblk = (N_NODES + 3) / 4;  // wave-per-node kernels, 4 waves/block

  // CSR build (atomic-free scatter: hist returns within-node offsets)
  hist_kernel<<<eblk, 256, 0, stream>>>(dst, deg, off);
  alloc_kernel<<<nblk, 256, 0, stream>>>(deg, gctr, rowstart);
  scatter_kernel<<<eblk, 256, 0, stream>>>(src, dst, rowstart, off, src_perm);

  // Layer 0 (+ P1 projection)
  fc0_kernel<<<nblk, 256, 0, stream>>>(x, fc0_w, fc0_b, u1, h0, P1);

  // FeaStConv 1: q (once per edge) -> edge-parallel agg -> GEMM
  q_kernel<<<wblk, 256, 0, stream>>>(rowstart, deg, src_perm, P1, c1, q_perm);
  agg1_kernel<<<wblk, 256, 0, stream>>>(rowstart, deg, src_perm, q_perm, h0, A);
  gemm1_kernel<<<(N_NODES + 63) / 64, 256, 0, stream>>>(deg, A, w1, b1, h1);

  // FeaStConv 2
  proj2_kernel<<<nblk, 256, 0, stream>>>(h1, u2, P2);
  q_kernel<<<wblk, 256, 0, stream>>>(rowstart, deg, src_perm, P2, c2, q_perm);
  agg2_kernel<<<wblk, 256, 0, stream>>>(rowstart, deg, src_perm, q_perm, h1, A);
  gemm2_kernel<<<(N_NODES + 31) / 32, 256, 0, stream>>>(deg, A, w2, b2, h2);

  // Pool + head
  int pblk = (N_NODES + POOL_CHUNK * 4 - 1) / (POOL_CHUNK * 4);
  pool_kernel<<<pblk, 256, 0, stream>>>(h2, batch, gsum, gcnt);
  head_kernel<<<1, 128, 0, stream>>>(gsum, gcnt, fc1_w, fc1_b, out);
}

// Round 11
// 281.686 us; speedup vs baseline: 1.4263x; 1.0713x over previous
//
#include <hip/hip_runtime.h>

#define N_NODES 50000
#define N_EDGES 800000
#define HEADS 4
#define NUM_GRAPHS 8

// ============ CSR build ============
// off[e] = arrival index of edge e within its dst node (atomic return value).
__global__ __launch_bounds__(256) void hist_kernel(const int* __restrict__ dst,
                                                   int* __restrict__ deg,
                                                   int* __restrict__ off) {
  int e = blockIdx.x * blockDim.x + threadIdx.x;
  if (e < N_EDGES) off[e] = atomicAdd(&deg[dst[e]], 1);
}

// Wave-aggregated bump allocation: rowstart[i] = arbitrary contiguous segment
// of length deg[i]. Cross-node order is irrelevant for correctness.
__global__ __launch_bounds__(256) void alloc_kernel(const int* __restrict__ deg,
                                                    int* __restrict__ gctr,
                                                    int* __restrict__ rowstart) {
  int i = blockIdx.x * blockDim.x + threadIdx.x;
  int lane = threadIdx.x & 63;
  int d = (i < N_NODES) ? deg[i] : 0;
  int pre = d;
#pragma unroll
  for (int offd = 1; offd < 64; offd <<= 1) {
    int v = __shfl_up(pre, offd, 64);
    if (lane >= offd) pre += v;
  }
  int total = __shfl(pre, 63, 64);
  int base = 0;
  if (lane == 63) base = atomicAdd(gctr, total);
  base = __shfl(base, 63, 64);
  if (i < N_NODES) rowstart[i] = base + pre - d;
}

// sd[rowstart[dst]+off] = {src, dst} — 8B random write costs the same 64B
// dirty line as the old 4B write; dst comes along for free.
__global__ __launch_bounds__(256) void scatter_kernel(const int* __restrict__ src,
                                                      const int* __restrict__ dst,
                                                      const int* __restrict__ rowstart,
                                                      const int* __restrict__ off,
                                                      int2* __restrict__ sd) {
  int e = blockIdx.x * blockDim.x + threadIdx.x;
  if (e >= N_EDGES) return;
  int d = dst[e];
  int p = rowstart[d] + off[e];
  sd[p] = make_int2(src[e], d);
}

// ============ fc0: h0 = relu(x@W0+b0) [N,16]; P1[n,h] = h0[n]·u1[:,h] ============
__global__ __launch_bounds__(256) void fc0_kernel(
    const float* __restrict__ x,
    const float* __restrict__ fc0_w, const float* __restrict__ fc0_b,
    const float* __restrict__ u1,
    float* __restrict__ h0, float* __restrict__ P1) {
  __shared__ float sW0[3 * 16];
  __shared__ float sB0[16];
  __shared__ float sU[16 * 4];
  for (int i = threadIdx.x; i < 48; i += blockDim.x) sW0[i] = fc0_w[i];
  for (int i = threadIdx.x; i < 16; i += blockDim.x) sB0[i] = fc0_b[i];
  for (int i = threadIdx.x; i < 64; i += blockDim.x) sU[i] = u1[i];
  __syncthreads();
  int n = blockIdx.x * blockDim.x + threadIdx.x;
  if (n >= N_NODES) return;
  float x0 = x[n * 3 + 0], x1 = x[n * 3 + 1], x2 = x[n * 3 + 2];
  float h[16];
#pragma unroll
  for (int j = 0; j < 16; j++) {
    float v = x0 * sW0[0 * 16 + j] + x1 * sW0[1 * 16 + j] + x2 * sW0[2 * 16 + j] + sB0[j];
    h[j] = fmaxf(v, 0.f);
    h0[(size_t)n * 16 + j] = h[j];
  }
  float p0 = 0.f, p1 = 0.f, p2 = 0.f, p3 = 0.f;
#pragma unroll
  for (int j = 0; j < 16; j++) {
    p0 += h[j] * sU[j * 4 + 0];
    p1 += h[j] * sU[j * 4 + 1];
    p2 += h[j] * sU[j * 4 + 2];
    p3 += h[j] * sU[j * 4 + 3];
  }
  reinterpret_cast<float4*>(P1)[n] = make_float4(p0, p1, p2, p3);
}

// ============ Q kernel: flat thread-per-edge (full lane utilization) ============
__global__ __launch_bounds__(256) void q_kernel(
    const int2* __restrict__ sd,
    const float* __restrict__ P, const float* __restrict__ cb,
    float* __restrict__ q_perm) {
  int p = blockIdx.x * blockDim.x + threadIdx.x;
  if (p >= N_EDGES) return;
  int2 e = sd[p];
  float4 Ps = reinterpret_cast<const float4*>(P)[e.x];
  float4 Pd = reinterpret_cast<const float4*>(P)[e.y];
  float l0 = Ps.x - Pd.x + cb[0];
  float l1 = Ps.y - Pd.y + cb[1];
  float l2 = Ps.z - Pd.z + cb[2];
  float l3 = Ps.w - Pd.w + cb[3];
  float m = fmaxf(fmaxf(l0, l1), fmaxf(l2, l3));
  float e0v = __expf(l0 - m), e1v = __expf(l1 - m), e2v = __expf(l2 - m), e3v = __expf(l3 - m);
  float inv = 1.f / (e0v + e1v + e2v + e3v);
  reinterpret_cast<float4*>(q_perm)[p] =
      make_float4(e0v * inv, e1v * inv, e2v * inv, e3v * inv);
}

// ============ AGG layer 1 (CIN=16): 4 edges in parallel per wave ============
__global__ __launch_bounds__(256) void agg1_kernel(
    const int* __restrict__ rowstart, const int* __restrict__ deg,
    const int2* __restrict__ sd, const float* __restrict__ q_perm,
    const float* __restrict__ h0,
    float* __restrict__ A) {
  int wave = threadIdx.x >> 6;
  int lane = threadIdx.x & 63;
  int g = lane >> 4;
  int j = lane & 15;
  int node = blockIdx.x * 4 + wave;
  if (node >= N_NODES) return;
  int e0 = rowstart[node];
  int e1 = e0 + deg[node];
  const float4* q4 = reinterpret_cast<const float4*>(q_perm);
  float a0 = 0.f, a1 = 0.f, a2 = 0.f, a3 = 0.f;
  int p = e0;
  for (; p + 16 <= e1; p += 16) {
    int sA = sd[p + 0 + g].x;
    int sB = sd[p + 4 + g].x;
    int sC = sd[p + 8 + g].x;
    int sD = sd[p + 12 + g].x;
    float4 qA = q4[p + 0 + g];
    float4 qB = q4[p + 4 + g];
    float4 qC = q4[p + 8 + g];
    float4 qD = q4[p + 12 + g];
    float fA = h0[(size_t)sA * 16 + j];
    float fB = h0[(size_t)sB * 16 + j];
    float fC = h0[(size_t)sC * 16 + j];
    float fD = h0[(size_t)sD * 16 + j];
    a0 += qA.x * fA + qB.x * fB + qC.x * fC + qD.x * fD;
    a1 += qA.y * fA + qB.y * fB + qC.y * fC + qD.y * fD;
    a2 += qA.z * fA + qB.z * fB + qC.z * fC + qD.z * fD;
    a3 += qA.w * fA + qB.w * fB + qC.w * fC + qD.w * fD;
  }
  for (; p + 4 <= e1; p += 4) {
    int s = sd[p + g].x;
    float4 q = q4[p + g];
    float f = h0[(size_t)s * 16 + j];
    a0 += q.x * f; a1 += q.y * f; a2 += q.z * f; a3 += q.w * f;
  }
  int rem = e1 - p;
  if (g < rem) {
    int s = sd[p + g].x;
    float4 q = q4[p + g];
    float f = h0[(size_t)s * 16 + j];
    a0 += q.x * f; a1 += q.y * f; a2 += q.z * f; a3 += q.w * f;
  }
  a0 += __shfl_xor(a0, 16, 64); a0 += __shfl_xor(a0, 32, 64);
  a1 += __shfl_xor(a1, 16, 64); a1 += __shfl_xor(a1, 32, 64);
  a2 += __shfl_xor(a2, 16, 64); a2 += __shfl_xor(a2, 32, 64);
  a3 += __shfl_xor(a3, 16, 64); a3 += __shfl_xor(a3, 32, 64);
  float o = (g == 0) ? a0 : (g == 1) ? a1 : (g == 2) ? a2 : a3;
  A[(size_t)node * 64 + lane] = o;  // A[node][g*16+j]
}

// ============ AGG layer 2 (CIN=32): 2 edges in parallel per wave ============
__global__ __launch_bounds__(256) void agg2_kernel(
    const int* __restrict__ rowstart, const int* __restrict__ deg,
    const int2* __restrict__ sd, const float* __restrict__ q_perm,
    const float* __restrict__ h1,
    float* __restrict__ A) {
  int wave = threadIdx.x >> 6;
  int lane = threadIdx.x & 63;
  int g = lane >> 5;
  int j = lane & 31;
  int node = blockIdx.x * 4 + wave;
  if (node >= N_NODES) return;
  int e0 = rowstart[node];
  int e1 = e0 + deg[node];
  const float4* q4 = reinterpret_cast<const float4*>(q_perm);
  float a0 = 0.f, a1 = 0.f, a2 = 0.f, a3 = 0.f;
  int p = e0;
  for (; p + 8 <= e1; p += 8) {
    int sA = sd[p + 0 + g].x;
    int sB = sd[p + 2 + g].x;
    int sC = sd[p + 4 + g].x;
    int sD = sd[p + 6 + g].x;
    float4 qA = q4[p + 0 + g];
    float4 qB = q4[p + 2 + g];
    float4 qC = q4[p + 4 + g];
    float4 qD = q4[p + 6 + g];
    float fA = h1[(size_t)sA * 32 + j];
    float fB = h1[(size_t)sB * 32 + j];
    float fC = h1[(size_t)sC * 32 + j];
    float fD = h1[(size_t)sD * 32 + j];
    a0 += qA.x * fA + qB.x * fB + qC.x * fC + qD.x * fD;
    a1 += qA.y * fA + qB.y * fB + qC.y * fC + qD.y * fD;
    a2 += qA.z * fA + qB.z * fB + qC.z * fC + qD.z * fD;
    a3 += qA.w * fA + qB.w * fB + qC.w * fC + qD.w * fD;
  }
  for (; p + 2 <= e1; p += 2) {
    int s = sd[p + g].x;
    float4 q = q4[p + g];
    float f = h1[(size_t)s * 32 + j];
    a0 += q.x * f; a1 += q.y * f; a2 += q.z * f; a3 += q.w * f;
  }
  int rem = e1 - p;
  if (g < rem) {
    int s = sd[p + g].x;
    float4 q = q4[p + g];
    float f = h1[(size_t)s * 32 + j];
    a0 += q.x * f; a1 += q.y * f; a2 += q.z * f; a3 += q.w * f;
  }
  a0 += __shfl_xor(a0, 32, 64);
  a1 += __shfl_xor(a1, 32, 64);
  a2 += __shfl_xor(a2, 32, 64);
  a3 += __shfl_xor(a3, 32, 64);
  float oa = (g == 0) ? a0 : a1;
  float ob = (g == 0) ? a2 : a3;
  A[(size_t)node * 128 + lane] = oa;        // [g*32+j]
  A[(size_t)node * 128 + 64 + lane] = ob;   // [(g+2)*32+j]
}

// ============ GEMM1 + fused proj2: h1 = relu((A1@B1)/deg + b1); P2 = h1·u2 ============
// thread = (2 nodes, 4 channels); P2 via 8-lane xor-shuffle reduction.
__global__ __launch_bounds__(256) void gemm1_kernel(
    const int* __restrict__ deg, const float* __restrict__ A,
    const float* __restrict__ w1, const float* __restrict__ b1,
    const float* __restrict__ u2,
    float* __restrict__ h1, float* __restrict__ P2) {
  __shared__ float sB[64 * 32];   // 8 KB; sB[k][c] = B1[k][c]
  __shared__ float sU[32 * 4];    // u2
  for (int i = threadIdx.x; i < 64 * 32; i += 256) {
    int hj = i / 32, c = i % 32;
    sB[i] = w1[(hj % 16) * 128 + (hj / 16) * 32 + c];
  }
  for (int i = threadIdx.x; i < 128; i += 256) sU[i] = u2[i];
  __syncthreads();
  const float4* sB4 = reinterpret_cast<const float4*>(sB);
  int c4 = threadIdx.x & 7;       // 8 float4 slots = 32 channels
  int g = threadIdx.x >> 3;       // 32 pairs x 2 nodes = 64 nodes/block
  int n0 = blockIdx.x * 64 + g * 2;
  int n1 = n0 + 1;
  int na = min(n0, N_NODES - 1);
  int nb = min(n1, N_NODES - 1);
  const float4* A0 = reinterpret_cast<const float4*>(A + (size_t)na * 64);
  const float4* A1 = reinterpret_cast<const float4*>(A + (size_t)nb * 64);
  float4 bc = reinterpret_cast<const float4*>(b1)[c4];
  float4 acc0 = {0, 0, 0, 0}, acc1 = {0, 0, 0, 0};
#pragma unroll 2
  for (int k4 = 0; k4 < 16; k4++) {
    float4 a0 = A0[k4];
    float4 a1 = A1[k4];
    float4 w0 = sB4[(4 * k4 + 0) * 8 + c4];
    float4 wv1 = sB4[(4 * k4 + 1) * 8 + c4];
    float4 w2v = sB4[(4 * k4 + 2) * 8 + c4];
    float4 w3 = sB4[(4 * k4 + 3) * 8 + c4];
    acc0.x += a0.x * w0.x + a0.y * wv1.x + a0.z * w2v.x + a0.w * w3.x;
    acc0.y += a0.x * w0.y + a0.y * wv1.y + a0.z * w2v.y + a0.w * w3.y;
    acc0.z += a0.x * w0.z + a0.y * wv1.z + a0.z * w2v.z + a0.w * w3.z;
    acc0.w += a0.x * w0.w + a0.y * wv1.w + a0.z * w2v.w + a0.w * w3.w;
    acc1.x += a1.x * w0.x + a1.y * wv1.x + a1.z * w2v.x + a1.w * w3.x;
    acc1.y += a1.x * w0.y + a1.y * wv1.y + a1.z * w2v.y + a1.w * w3.y;
    acc1.z += a1.x * w0.z + a1.y * wv1.z + a1.z * w2v.z + a1.w * w3.z;
    acc1.w += a1.x * w0.w + a1.y * wv1.w + a1.z * w2v.w + a1.w * w3.w;
  }
  float inv0 = 1.f / fmaxf((float)deg[na], 1.f);
  float inv1 = 1.f / fmaxf((float)deg[nb], 1.f);
  float4 o0 = {fmaxf(acc0.x * inv0 + bc.x, 0.f), fmaxf(acc0.y * inv0 + bc.y, 0.f),
               fmaxf(acc0.z * inv0 + bc.z, 0.f), fmaxf(acc0.w * inv0 + bc.w, 0.f)};
  float4 o1 = {fmaxf(acc1.x * inv1 + bc.x, 0.f), fmaxf(acc1.y * inv1 + bc.y, 0.f),
               fmaxf(acc1.z * inv1 + bc.z, 0.f), fmaxf(acc1.w * inv1 + bc.w, 0.f)};
  if (n0 < N_NODES) reinterpret_cast<float4*>(h1 + (size_t)n0 * 32)[c4] = o0;
  if (n1 < N_NODES) reinterpret_cast<float4*>(h1 + (size_t)n1 * 32)[c4] = o1;
  // P2 partials over this thread's 4 channels, both nodes
  float pa[4] = {0, 0, 0, 0}, pb[4] = {0, 0, 0, 0};
#pragma unroll
  for (int k = 0; k < 4; k++) {
    int c = 4 * c4 + k;
    float v0 = k == 0 ? o0.x : k == 1 ? o0.y : k == 2 ? o0.z : o0.w;
    float v1 = k == 0 ? o1.x : k == 1 ? o1.y : k == 2 ? o1.z : o1.w;
#pragma unroll
    for (int hh = 0; hh < 4; hh++) {
      pa[hh] += v0 * sU[c * 4 + hh];
      pb[hh] += v1 * sU[c * 4 + hh];
    }
  }
#pragma unroll
  for (int msk = 1; msk <= 4; msk <<= 1) {
#pragma unroll
    for (int hh = 0; hh < 4; hh++) {
      pa[hh] += __shfl_xor(pa[hh], msk, 64);
      pb[hh] += __shfl_xor(pb[hh], msk, 64);
    }
  }
  if (c4 == 0) {
    if (n0 < N_NODES)
      reinterpret_cast<float4*>(P2)[n0] = make_float4(pa[0], pa[1], pa[2], pa[3]);
    if (n1 < N_NODES)
      reinterpret_cast<float4*>(P2)[n1] = make_float4(pb[0], pb[1], pb[2], pb[3]);
  }
}

// ============ GEMM2: h2 = relu((A2 @ B2)/deg + b2), A2:[N,128], B2:[128,64] ============
__global__ __launch_bounds__(256) void gemm2_kernel(
    const int* __restrict__ deg, const float* __restrict__ A,
    const float* __restrict__ w2, const float* __restrict__ b2,
    float* __restrict__ h2) {
  __shared__ float sB[128 * 64];  // 32 KB; sB[k][c] = B2[k][c]
  for (int i = threadIdx.x; i < 128 * 64; i += 256) {
    int hj = i / 64, c = i % 64;
    sB[i] = w2[(hj % 32) * 256 + (hj / 32) * 64 + c];
  }
  __syncthreads();
  const float4* sB4 = reinterpret_cast<const float4*>(sB);
  int c4 = threadIdx.x & 15;      // 16 float4 slots = 64 channels
  int g = threadIdx.x >> 4;       // 16 pairs x 2 nodes = 32 nodes/block
  int n0 = blockIdx.x * 32 + g * 2;
  int n1 = n0 + 1;
  int na = min(n0, N_NODES - 1);
  int nb = min(n1, N_NODES - 1);
  const float4* A0 = reinterpret_cast<const float4*>(A + (size_t)na * 128);
  const float4* A1 = reinterpret_cast<const float4*>(A + (size_t)nb * 128);
  float4 bc = reinterpret_cast<const float4*>(b2)[c4];
  float4 acc0 = {0, 0, 0, 0}, acc1 = {0, 0, 0, 0};
#pragma unroll 2
  for (int k4 = 0; k4 < 32; k4++) {
    float4 a0 = A0[k4];
    float4 a1 = A1[k4];
    float4 w0 = sB4[(4 * k4 + 0) * 16 + c4];
    float4 wv1 = sB4[(4 * k4 + 1) * 16 + c4];
    float4 w2v = sB4[(4 * k4 + 2) * 16 + c4];
    float4 w3 = sB4[(4 * k4 + 3) * 16 + c4];
    acc0.x += a0.x * w0.x + a0.y * wv1.x + a0.z * w2v.x + a0.w * w3.x;
    acc0.y += a0.x * w0.y + a0.y * wv1.y + a0.z * w2v.y + a0.w * w3.y;
    acc0.z += a0.x * w0.z + a0.y * wv1.z + a0.z * w2v.z + a0.w * w3.z;
    acc0.w += a0.x * w0.w + a0.y * wv1.w + a0.z * w2v.w + a0.w * w3.w;
    acc1.x += a1.x * w0.x + a1.y * wv1.x + a1.z * w2v.x + a1.w * w3.x;
    acc1.y += a1.x * w0.y + a1.y * wv1.y + a1.z * w2v.y + a1.w * w3.y;
    acc1.z += a1.x * w0.z + a1.y * wv1.z + a1.z * w2v.z + a1.w * w3.z;
    acc1.w += a1.x * w0.w + a1.y * wv1.w + a1.z * w2v.w + a1.w * w3.w;
  }
  if (n0 < N_NODES) {
    float inv = 1.f / fmaxf((float)deg[n0], 1.f);
    float4 o = {fmaxf(acc0.x * inv + bc.x, 0.f), fmaxf(acc0.y * inv + bc.y, 0.f),
                fmaxf(acc0.z * inv + bc.z, 0.f), fmaxf(acc0.w * inv + bc.w, 0.f)};
    reinterpret_cast<float4*>(h2 + (size_t)n0 * 64)[c4] = o;
  }
  if (n1 < N_NODES) {
    float inv = 1.f / fmaxf((float)deg[n1], 1.f);
    float4 o = {fmaxf(acc1.x * inv + bc.x, 0.f), fmaxf(acc1.y * inv + bc.y, 0.f),
                fmaxf(acc1.z * inv + bc.z, 0.f), fmaxf(acc1.w * inv + bc.w, 0.f)};
    reinterpret_cast<float4*>(h2 + (size_t)n1 * 64)[c4] = o;
  }
}

// ============ Pool: per-graph mean of h2 (batch sorted) ============
#define POOL_CHUNK 64
__global__ __launch_bounds__(256) void pool_kernel(
    const float* __restrict__ h2, const int* __restrict__ batch,
    float* __restrict__ gsum, float* __restrict__ gcnt) {
  int grp = threadIdx.x / 64;
  int c = threadIdx.x % 64;
  int n0 = (blockIdx.x * 4 + grp) * POOL_CHUNK;
  int n1 = min(n0 + POOL_CHUNK, N_NODES);
  if (n0 >= N_NODES) return;
  float acc = 0.f;
  float cacc = 0.f;
  int curg = batch[n0];
  for (int n = n0; n < n1; n++) {
    int g = batch[n];
    float v = h2[(size_t)n * 64 + c];
    if (g != curg) {
      atomicAdd(&gsum[curg * 64 + c], acc);
      if (c == 0) atomicAdd(&gcnt[curg], cacc);
      acc = 0.f;
      cacc = 0.f;
      curg = g;
    }
    acc += v;
    cacc += 1.f;
  }
  atomicAdd(&gsum[curg * 64 + c], acc);
  if (c == 0) atomicAdd(&gcnt[curg], cacc);
}

// ============ Head: out = (gsum/gcnt) @ fc1_w + fc1_b ============
__global__ __launch_bounds__(128) void head_kernel(
    const float* __restrict__ gsum, const float* __restrict__ gcnt,
    const float* __restrict__ fc1_w, const float* __restrict__ fc1_b,
    float* __restrict__ out) {
  int t = threadIdx.x;
  if (t >= NUM_GRAPHS * 10) return;
  int g = t / 10, k = t % 10;
  float inv = 1.f / fmaxf(gcnt[g], 1.f);
  float s = fc1_b[k];
#pragma unroll
  for (int c = 0; c < 64; c++) s += gsum[g * 64 + c] * inv * fc1_w[c * 10 + k];
  out[g * 10 + k] = s;
}

extern "C" void kernel_launch(void* const* d_in, const int* in_sizes, int n_in,
                              void* d_out, int out_size, void* d_ws, size_t ws_size,
                              hipStream_t stream) {
  const float* x = (const float*)d_in[0];
  const int* edge_index = (const int*)d_in[1];
  const int* batch = (const int*)d_in[2];
  const float* fc0_w = (const float*)d_in[3];
  const float* fc0_b = (const float*)d_in[4];
  const float* u1 = (const float*)d_in[5];
  const float* c1 = (const float*)d_in[6];
  const float* w1 = (const float*)d_in[7];
  const float* b1 = (const float*)d_in[8];
  const float* u2 = (const float*)d_in[9];
  const float* c2 = (const float*)d_in[10];
  const float* w2 = (const float*)d_in[11];
  const float* b2 = (const float*)d_in[12];
  const float* fc1_w = (const float*)d_in[13];
  const float* fc1_b = (const float*)d_in[14];
  float* out = (float*)d_out;

  const int* src = edge_index;            // x_j
  const int* dst = edge_index + N_EDGES;  // x_i

  // ---- workspace layout (4-byte words) ----
  // Zero region first: deg(N) @0, gctr @50000, pad, gsum @50004 (512), gcnt @50516 (8)
  char* wsb = (char*)d_ws;
  int* deg = (int*)wsb;                          // N
  int* gctr = deg + N_NODES;                     // 1  @50000
  float* gsum = (float*)wsb + 50004;             // 512
  float* gcnt = gsum + NUM_GRAPHS * 64;          // 8   (end 50524)
  int* rowstart = (int*)wsb + 50524;             // N   [50524,100524)
  int* off = rowstart + N_NODES;                 // E   [100524,900524)
  int2* sd = (int2*)((int*)wsb + 900524);        // E int2 [900524,2500524)
  float* q_perm = (float*)wsb + 2500524;         // E*4 [2500524,5700524)
  float* h0 = q_perm + (size_t)N_EDGES * 4;      // N*16
  float* h1 = h0 + (size_t)N_NODES * 16;         // N*32
  float* h2 = h1 + (size_t)N_NODES * 32;         // N*64
  float* A = h2 + (size_t)N_NODES * 64;          // N*128
  float* P1 = A + (size_t)N_NODES * 128;         // N*4
  float* P2 = P1 + (size_t)N_NODES * 4;          // N*4

  // one memset covers deg + gctr + pad + gsum + gcnt
  hipMemsetAsync(d_ws, 0, 50524 * sizeof(int), stream);

  int nblk = (N_NODES + 255) / 256;
  int eblk = (N_EDGES + 255) / 256;
  int wblk = (N_NODES + 3) / 4;  // wave-per-node kernels, 4 waves/block

  // CSR build (atomic-free scatter; sd packs {src,dst})
  hist_kernel<<<eblk, 256, 0, stream>>>(dst, deg, off);
  alloc_kernel<<<nblk, 256, 0, stream>>>(deg, gctr, rowstart);
  scatter_kernel<<<eblk, 256, 0, stream>>>(src, dst, rowstart, off, sd);

  // Layer 0 (+ P1 projection)
  fc0_kernel<<<nblk, 256, 0, stream>>>(x, fc0_w, fc0_b, u1, h0, P1);

  // FeaStConv 1: flat q -> edge-parallel agg -> GEMM (+ fused P2 projection)
  q_kernel<<<eblk, 256, 0, stream>>>(sd, P1, c1, q_perm);
  agg1_kernel<<<wblk, 256, 0, stream>>>(rowstart, deg, sd, q_perm, h0, A);
  gemm1_kernel<<<(N_NODES + 63) / 64, 256, 0, stream>>>(deg, A, w1, b1, u2, h1, P2);

  // FeaStConv 2
  q_kernel<<<eblk, 256, 0, stream>>>(sd, P2, c2, q_perm);
  agg2_kernel<<<wblk, 256, 0, stream>>>(rowstart, deg, sd, q_perm, h1, A);
  gemm2_kernel<<<(N_NODES + 31) / 32, 256, 0, stream>>>(deg, A, w2, b2, h2);

  // Pool + head
  int pblk = (N_NODES + POOL_CHUNK * 4 - 1) / (POOL_CHUNK * 4);
  pool_kernel<<<pblk, 256, 0, stream>>>(h2, batch, gsum, gcnt);
  head_kernel<<<1, 128, 0, stream>>>(gsum, gcnt, fc1_w, fc1_b, out);
}

// Round 12
// 274.483 us; speedup vs baseline: 1.4638x; 1.0262x over previous
//
#include <hip/hip_runtime.h>

#define N_NODES 50000
#define N_EDGES 800000
#define HEADS 4
#define NUM_GRAPHS 8

#define EBLK ((N_EDGES + 255) / 256)   // 3125
#define NBLK ((N_NODES + 255) / 256)   // 196

// ============ Fused: hist (edge blocks) + fc0/P1 (node blocks) ============
// off[e] = arrival index of edge e within its dst node (atomic return value).
__global__ __launch_bounds__(256) void hist_fc0_kernel(
    const int* __restrict__ dst, int* __restrict__ deg, int* __restrict__ off,
    const float* __restrict__ x,
    const float* __restrict__ fc0_w, const float* __restrict__ fc0_b,
    const float* __restrict__ u1,
    float* __restrict__ h0, float* __restrict__ P1) {
  if (blockIdx.x < EBLK) {
    int e = blockIdx.x * 256 + threadIdx.x;
    if (e < N_EDGES) off[e] = atomicAdd(&deg[dst[e]], 1);
    return;
  }
  __shared__ float sW0[3 * 16];
  __shared__ float sB0[16];
  __shared__ float sU[16 * 4];
  for (int i = threadIdx.x; i < 48; i += 256) sW0[i] = fc0_w[i];
  for (int i = threadIdx.x; i < 16; i += 256) sB0[i] = fc0_b[i];
  for (int i = threadIdx.x; i < 64; i += 256) sU[i] = u1[i];
  __syncthreads();
  int n = (blockIdx.x - EBLK) * 256 + threadIdx.x;
  if (n >= N_NODES) return;
  float x0 = x[n * 3 + 0], x1 = x[n * 3 + 1], x2 = x[n * 3 + 2];
  float h[16];
#pragma unroll
  for (int j = 0; j < 16; j++) {
    float v = x0 * sW0[0 * 16 + j] + x1 * sW0[1 * 16 + j] + x2 * sW0[2 * 16 + j] + sB0[j];
    h[j] = fmaxf(v, 0.f);
    h0[(size_t)n * 16 + j] = h[j];
  }
  float p0 = 0.f, p1 = 0.f, p2 = 0.f, p3 = 0.f;
#pragma unroll
  for (int j = 0; j < 16; j++) {
    p0 += h[j] * sU[j * 4 + 0];
    p1 += h[j] * sU[j * 4 + 1];
    p2 += h[j] * sU[j * 4 + 2];
    p3 += h[j] * sU[j * 4 + 3];
  }
  reinterpret_cast<float4*>(P1)[n] = make_float4(p0, p1, p2, p3);
}

// Wave-aggregated bump allocation: rowstart[i] = arbitrary contiguous segment.
__global__ __launch_bounds__(256) void alloc_kernel(const int* __restrict__ deg,
                                                    int* __restrict__ gctr,
                                                    int* __restrict__ rowstart) {
  int i = blockIdx.x * blockDim.x + threadIdx.x;
  int lane = threadIdx.x & 63;
  int d = (i < N_NODES) ? deg[i] : 0;
  int pre = d;
#pragma unroll
  for (int offd = 1; offd < 64; offd <<= 1) {
    int v = __shfl_up(pre, offd, 64);
    if (lane >= offd) pre += v;
  }
  int total = __shfl(pre, 63, 64);
  int base = 0;
  if (lane == 63) base = atomicAdd(gctr, total);
  base = __shfl(base, 63, 64);
  if (i < N_NODES) rowstart[i] = base + pre - d;
}

// src_perm[rowstart[dst]+off] = src — atomic-free random scatter.
__global__ __launch_bounds__(256) void scatter_kernel(const int* __restrict__ src,
                                                      const int* __restrict__ dst,
                                                      const int* __restrict__ rowstart,
                                                      const int* __restrict__ off,
                                                      int* __restrict__ src_perm) {
  int e = blockIdx.x * blockDim.x + threadIdx.x;
  if (e >= N_EDGES) return;
  src_perm[rowstart[dst[e]] + off[e]] = src[e];
}

// per-edge softmax helper (in-register, no cross-lane)
__device__ __forceinline__ float4 edge_q(float4 Ps, float b0, float b1, float b2, float b3) {
  float l0 = Ps.x + b0, l1 = Ps.y + b1, l2 = Ps.z + b2, l3 = Ps.w + b3;
  float m = fmaxf(fmaxf(l0, l1), fmaxf(l2, l3));
  float e0 = __expf(l0 - m), e1 = __expf(l1 - m), e2 = __expf(l2 - m), e3 = __expf(l3 - m);
  float inv = 1.f / (e0 + e1 + e2 + e3);
  return make_float4(e0 * inv, e1 * inv, e2 * inv, e3 * inv);
}

// ============ AGG1 + inline q (CIN=16): 4 edges in parallel per wave ============
// lane = g*16+j. Each lane computes its edge's 4-head softmax from P (edge-
// parallel: 4 softmax sequences per 16 edges at wave level — ~free vs gathers).
__global__ __launch_bounds__(256) void agg1_kernel(
    const int* __restrict__ rowstart, const int* __restrict__ deg,
    const int* __restrict__ src_perm,
    const float* __restrict__ P1, const float* __restrict__ c1,
    const float* __restrict__ h0,
    float* __restrict__ A) {
  int wave = threadIdx.x >> 6;
  int lane = threadIdx.x & 63;
  int g = lane >> 4;
  int j = lane & 15;
  int node = blockIdx.x * 4 + wave;
  if (node >= N_NODES) return;
  float4 Pd = reinterpret_cast<const float4*>(P1)[node];
  float b0 = c1[0] - Pd.x, b1 = c1[1] - Pd.y, b2 = c1[2] - Pd.z, b3 = c1[3] - Pd.w;
  int e0 = rowstart[node];
  int e1 = e0 + deg[node];
  const float4* P4 = reinterpret_cast<const float4*>(P1);
  float a0 = 0.f, a1 = 0.f, a2 = 0.f, a3 = 0.f;
  int p = e0;
  for (; p + 16 <= e1; p += 16) {
    int sA = src_perm[p + 0 + g];
    int sB = src_perm[p + 4 + g];
    int sC = src_perm[p + 8 + g];
    int sD = src_perm[p + 12 + g];
    float4 PA = P4[sA];
    float4 PB = P4[sB];
    float4 PC = P4[sC];
    float4 PD = P4[sD];
    float fA = h0[(size_t)sA * 16 + j];
    float fB = h0[(size_t)sB * 16 + j];
    float fC = h0[(size_t)sC * 16 + j];
    float fD = h0[(size_t)sD * 16 + j];
    float4 qA = edge_q(PA, b0, b1, b2, b3);
    float4 qB = edge_q(PB, b0, b1, b2, b3);
    float4 qC = edge_q(PC, b0, b1, b2, b3);
    float4 qD = edge_q(PD, b0, b1, b2, b3);
    a0 += qA.x * fA + qB.x * fB + qC.x * fC + qD.x * fD;
    a1 += qA.y * fA + qB.y * fB + qC.y * fC + qD.y * fD;
    a2 += qA.z * fA + qB.z * fB + qC.z * fC + qD.z * fD;
    a3 += qA.w * fA + qB.w * fB + qC.w * fC + qD.w * fD;
  }
  for (; p + 4 <= e1; p += 4) {
    int s = src_perm[p + g];
    float4 Ps = P4[s];
    float f = h0[(size_t)s * 16 + j];
    float4 q = edge_q(Ps, b0, b1, b2, b3);
    a0 += q.x * f; a1 += q.y * f; a2 += q.z * f; a3 += q.w * f;
  }
  int rem = e1 - p;
  if (g < rem) {
    int s = src_perm[p + g];
    float4 Ps = P4[s];
    float f = h0[(size_t)s * 16 + j];
    float4 q = edge_q(Ps, b0, b1, b2, b3);
    a0 += q.x * f; a1 += q.y * f; a2 += q.z * f; a3 += q.w * f;
  }
  a0 += __shfl_xor(a0, 16, 64); a0 += __shfl_xor(a0, 32, 64);
  a1 += __shfl_xor(a1, 16, 64); a1 += __shfl_xor(a1, 32, 64);
  a2 += __shfl_xor(a2, 16, 64); a2 += __shfl_xor(a2, 32, 64);
  a3 += __shfl_xor(a3, 16, 64); a3 += __shfl_xor(a3, 32, 64);
  float o = (g == 0) ? a0 : (g == 1) ? a1 : (g == 2) ? a2 : a3;
  A[(size_t)node * 64 + lane] = o;  // A[node][g*16+j]
}

// ============ AGG2 + inline q (CIN=32): 2 edges in parallel per wave ============
__global__ __launch_bounds__(256) void agg2_kernel(
    const int* __restrict__ rowstart, const int* __restrict__ deg,
    const int* __restrict__ src_perm,
    const float* __restrict__ P2, const float* __restrict__ c2,
    const float* __restrict__ h1,
    float* __restrict__ A) {
  int wave = threadIdx.x >> 6;
  int lane = threadIdx.x & 63;
  int g = lane >> 5;
  int j = lane & 31;
  int node = blockIdx.x * 4 + wave;
  if (node >= N_NODES) return;
  float4 Pd = reinterpret_cast<const float4*>(P2)[node];
  float b0 = c2[0] - Pd.x, b1 = c2[1] - Pd.y, b2 = c2[2] - Pd.z, b3 = c2[3] - Pd.w;
  int e0 = rowstart[node];
  int e1 = e0 + deg[node];
  const float4* P4 = reinterpret_cast<const float4*>(P2);
  float a0 = 0.f, a1 = 0.f, a2 = 0.f, a3 = 0.f;
  int p = e0;
  for (; p + 8 <= e1; p += 8) {
    int sA = src_perm[p + 0 + g];
    int sB = src_perm[p + 2 + g];
    int sC = src_perm[p + 4 + g];
    int sD = src_perm[p + 6 + g];
    float4 PA = P4[sA];
    float4 PB = P4[sB];
    float4 PC = P4[sC];
    float4 PD = P4[sD];
    float fA = h1[(size_t)sA * 32 + j];
    float fB = h1[(size_t)sB * 32 + j];
    float fC = h1[(size_t)sC * 32 + j];
    float fD = h1[(size_t)sD * 32 + j];
    float4 qA = edge_q(PA, b0, b1, b2, b3);
    float4 qB = edge_q(PB, b0, b1, b2, b3);
    float4 qC = edge_q(PC, b0, b1, b2, b3);
    float4 qD = edge_q(PD, b0, b1, b2, b3);
    a0 += qA.x * fA + qB.x * fB + qC.x * fC + qD.x * fD;
    a1 += qA.y * fA + qB.y * fB + qC.y * fC + qD.y * fD;
    a2 += qA.z * fA + qB.z * fB + qC.z * fC + qD.z * fD;
    a3 += qA.w * fA + qB.w * fB + qC.w * fC + qD.w * fD;
  }
  for (; p + 2 <= e1; p += 2) {
    int s = src_perm[p + g];
    float4 Ps = P4[s];
    float f = h1[(size_t)s * 32 + j];
    float4 q = edge_q(Ps, b0, b1, b2, b3);
    a0 += q.x * f; a1 += q.y * f; a2 += q.z * f; a3 += q.w * f;
  }
  int rem = e1 - p;
  if (g < rem) {
    int s = src_perm[p + g];
    float4 Ps = P4[s];
    float f = h1[(size_t)s * 32 + j];
    float4 q = edge_q(Ps, b0, b1, b2, b3);
    a0 += q.x * f; a1 += q.y * f; a2 += q.z * f; a3 += q.w * f;
  }
  a0 += __shfl_xor(a0, 32, 64);
  a1 += __shfl_xor(a1, 32, 64);
  a2 += __shfl_xor(a2, 32, 64);
  a3 += __shfl_xor(a3, 32, 64);
  float oa = (g == 0) ? a0 : a1;
  float ob = (g == 0) ? a2 : a3;
  A[(size_t)node * 128 + lane] = oa;        // [g*32+j]
  A[(size_t)node * 128 + 64 + lane] = ob;   // [(g+2)*32+j]
}

// ============ GEMM1 + fused proj2: h1 = relu((A1@B1)/deg + b1); P2 = h1·u2 ============
__global__ __launch_bounds__(256) void gemm1_kernel(
    const int* __restrict__ deg, const float* __restrict__ A,
    const float* __restrict__ w1, const float* __restrict__ b1,
    const float* __restrict__ u2,
    float* __restrict__ h1, float* __restrict__ P2) {
  __shared__ float sB[64 * 32];   // 8 KB
  __shared__ float sU[32 * 4];
  for (int i = threadIdx.x; i < 64 * 32; i += 256) {
    int hj = i / 32, c = i % 32;
    sB[i] = w1[(hj % 16) * 128 + (hj / 16) * 32 + c];
  }
  for (int i = threadIdx.x; i < 128; i += 256) sU[i] = u2[i];
  __syncthreads();
  const float4* sB4 = reinterpret_cast<const float4*>(sB);
  int c4 = threadIdx.x & 7;
  int g = threadIdx.x >> 3;
  int n0 = blockIdx.x * 64 + g * 2;
  int n1 = n0 + 1;
  int na = min(n0, N_NODES - 1);
  int nb = min(n1, N_NODES - 1);
  const float4* A0 = reinterpret_cast<const float4*>(A + (size_t)na * 64);
  const float4* A1 = reinterpret_cast<const float4*>(A + (size_t)nb * 64);
  float4 bc = reinterpret_cast<const float4*>(b1)[c4];
  float4 acc0 = {0, 0, 0, 0}, acc1 = {0, 0, 0, 0};
#pragma unroll 2
  for (int k4 = 0; k4 < 16; k4++) {
    float4 a0 = A0[k4];
    float4 a1 = A1[k4];
    float4 w0 = sB4[(4 * k4 + 0) * 8 + c4];
    float4 wv1 = sB4[(4 * k4 + 1) * 8 + c4];
    float4 w2v = sB4[(4 * k4 + 2) * 8 + c4];
    float4 w3 = sB4[(4 * k4 + 3) * 8 + c4];
    acc0.x += a0.x * w0.x + a0.y * wv1.x + a0.z * w2v.x + a0.w * w3.x;
    acc0.y += a0.x * w0.y + a0.y * wv1.y + a0.z * w2v.y + a0.w * w3.y;
    acc0.z += a0.x * w0.z + a0.y * wv1.z + a0.z * w2v.z + a0.w * w3.z;
    acc0.w += a0.x * w0.w + a0.y * wv1.w + a0.z * w2v.w + a0.w * w3.w;
    acc1.x += a1.x * w0.x + a1.y * wv1.x + a1.z * w2v.x + a1.w * w3.x;
    acc1.y += a1.x * w0.y + a1.y * wv1.y + a1.z * w2v.y + a1.w * w3.y;
    acc1.z += a1.x * w0.z + a1.y * wv1.z + a1.z * w2v.z + a1.w * w3.z;
    acc1.w += a1.x * w0.w + a1.y * wv1.w + a1.z * w2v.w + a1.w * w3.w;
  }
  float inv0 = 1.f / fmaxf((float)deg[na], 1.f);
  float inv1 = 1.f / fmaxf((float)deg[nb], 1.f);
  float4 o0 = {fmaxf(acc0.x * inv0 + bc.x, 0.f), fmaxf(acc0.y * inv0 + bc.y, 0.f),
               fmaxf(acc0.z * inv0 + bc.z, 0.f), fmaxf(acc0.w * inv0 + bc.w, 0.f)};
  float4 o1 = {fmaxf(acc1.x * inv1 + bc.x, 0.f), fmaxf(acc1.y * inv1 + bc.y, 0.f),
               fmaxf(acc1.z * inv1 + bc.z, 0.f), fmaxf(acc1.w * inv1 + bc.w, 0.f)};
  if (n0 < N_NODES) reinterpret_cast<float4*>(h1 + (size_t)n0 * 32)[c4] = o0;
  if (n1 < N_NODES) reinterpret_cast<float4*>(h1 + (size_t)n1 * 32)[c4] = o1;
  float pa[4] = {0, 0, 0, 0}, pb[4] = {0, 0, 0, 0};
#pragma unroll
  for (int k = 0; k < 4; k++) {
    int c = 4 * c4 + k;
    float v0 = k == 0 ? o0.x : k == 1 ? o0.y : k == 2 ? o0.z : o0.w;
    float v1 = k == 0 ? o1.x : k == 1 ? o1.y : k == 2 ? o1.z : o1.w;
#pragma unroll
    for (int hh = 0; hh < 4; hh++) {
      pa[hh] += v0 * sU[c * 4 + hh];
      pb[hh] += v1 * sU[c * 4 + hh];
    }
  }
#pragma unroll
  for (int msk = 1; msk <= 4; msk <<= 1) {
#pragma unroll
    for (int hh = 0; hh < 4; hh++) {
      pa[hh] += __shfl_xor(pa[hh], msk, 64);
      pb[hh] += __shfl_xor(pb[hh], msk, 64);
    }
  }
  if (c4 == 0) {
    if (n0 < N_NODES)
      reinterpret_cast<float4*>(P2)[n0] = make_float4(pa[0], pa[1], pa[2], pa[3]);
    if (n1 < N_NODES)
      reinterpret_cast<float4*>(P2)[n1] = make_float4(pb[0], pb[1], pb[2], pb[3]);
  }
}

// ============ GEMM2: h2 = relu((A2 @ B2)/deg + b2), A2:[N,128], B2:[128,64] ============
__global__ __launch_bounds__(256) void gemm2_kernel(
    const int* __restrict__ deg, const float* __restrict__ A,
    const float* __restrict__ w2, const float* __restrict__ b2,
    float* __restrict__ h2) {
  __shared__ float sB[128 * 64];  // 32 KB
  for (int i = threadIdx.x; i < 128 * 64; i += 256) {
    int hj = i / 64, c = i % 64;
    sB[i] = w2[(hj % 32) * 256 + (hj / 32) * 64 + c];
  }
  __syncthreads();
  const float4* sB4 = reinterpret_cast<const float4*>(sB);
  int c4 = threadIdx.x & 15;
  int g = threadIdx.x >> 4;
  int n0 = blockIdx.x * 32 + g * 2;
  int n1 = n0 + 1;
  int na = min(n0, N_NODES - 1);
  int nb = min(n1, N_NODES - 1);
  const float4* A0 = reinterpret_cast<const float4*>(A + (size_t)na * 128);
  const float4* A1 = reinterpret_cast<const float4*>(A + (size_t)nb * 128);
  float4 bc = reinterpret_cast<const float4*>(b2)[c4];
  float4 acc0 = {0, 0, 0, 0}, acc1 = {0, 0, 0, 0};
#pragma unroll 2
  for (int k4 = 0; k4 < 32; k4++) {
    float4 a0 = A0[k4];
    float4 a1 = A1[k4];
    float4 w0 = sB4[(4 * k4 + 0) * 16 + c4];
    float4 wv1 = sB4[(4 * k4 + 1) * 16 + c4];
    float4 w2v = sB4[(4 * k4 + 2) * 16 + c4];
    float4 w3 = sB4[(4 * k4 + 3) * 16 + c4];
    acc0.x += a0.x * w0.x + a0.y * wv1.x + a0.z * w2v.x + a0.w * w3.x;
    acc0.y += a0.x * w0.y + a0.y * wv1.y + a0.z * w2v.y + a0.w * w3.y;
    acc0.z += a0.x * w0.z + a0.y * wv1.z + a0.z * w2v.z + a0.w * w3.z;
    acc0.w += a0.x * w0.w + a0.y * wv1.w + a0.z * w2v.w + a0.w * w3.w;
    acc1.x += a1.x * w0.x + a1.y * wv1.x + a1.z * w2v.x + a1.w * w3.x;
    acc1.y += a1.x * w0.y + a1.y * wv1.y + a1.z * w2v.y + a1.w * w3.y;
    acc1.z += a1.x * w0.z + a1.y * wv1.z + a1.z * w2v.z + a1.w * w3.z;
    acc1.w += a1.x * w0.w + a1.y * wv1.w + a1.z * w2v.w + a1.w * w3.w;
  }
  if (n0 < N_NODES) {
    float inv = 1.f / fmaxf((float)deg[n0], 1.f);
    float4 o = {fmaxf(acc0.x * inv + bc.x, 0.f), fmaxf(acc0.y * inv + bc.y, 0.f),
                fmaxf(acc0.z * inv + bc.z, 0.f), fmaxf(acc0.w * inv + bc.w, 0.f)};
    reinterpret_cast<float4*>(h2 + (size_t)n0 * 64)[c4] = o;
  }
  if (n1 < N_NODES) {
    float inv = 1.f / fmaxf((float)deg[n1], 1.f);
    float4 o = {fmaxf(acc1.x * inv + bc.x, 0.f), fmaxf(acc1.y * inv + bc.y, 0.f),
                fmaxf(acc1.z * inv + bc.z, 0.f), fmaxf(acc1.w * inv + bc.w, 0.f)};
    reinterpret_cast<float4*>(h2 + (size_t)n1 * 64)[c4] = o;
  }
}

// ============ Pool: per-graph mean of h2 (batch sorted) ============
#define POOL_CHUNK 64
__global__ __launch_bounds__(256) void pool_kernel(
    const float* __restrict__ h2, const int* __restrict__ batch,
    float* __restrict__ gsum, float* __restrict__ gcnt) {
  int grp = threadIdx.x / 64;
  int c = threadIdx.x % 64;
  int n0 = (blockIdx.x * 4 + grp) * POOL_CHUNK;
  int n1 = min(n0 + POOL_CHUNK, N_NODES);
  if (n0 >= N_NODES) return;
  float acc = 0.f;
  float cacc = 0.f;
  int curg = batch[n0];
  for (int n = n0; n < n1; n++) {
    int g = batch[n];
    float v = h2[(size_t)n * 64 + c];
    if (g != curg) {
      atomicAdd(&gsum[curg * 64 + c], acc);
      if (c == 0) atomicAdd(&gcnt[curg], cacc);
      acc = 0.f;
      cacc = 0.f;
      curg = g;
    }
    acc += v;
    cacc += 1.f;
  }
  atomicAdd(&gsum[curg * 64 + c], acc);
  if (c == 0) atomicAdd(&gcnt[curg], cacc);
}

// ============ Head: out = (gsum/gcnt) @ fc1_w + fc1_b ============
__global__ __launch_bounds__(128) void head_kernel(
    const float* __restrict__ gsum, const float* __restrict__ gcnt,
    const float* __restrict__ fc1_w, const float* __restrict__ fc1_b,
    float* __restrict__ out) {
  int t = threadIdx.x;
  if (t >= NUM_GRAPHS * 10) return;
  int g = t / 10, k = t % 10;
  float inv = 1.f / fmaxf(gcnt[g], 1.f);
  float s = fc1_b[k];
#pragma unroll
  for (int c = 0; c < 64; c++) s += gsum[g * 64 + c] * inv * fc1_w[c * 10 + k];
  out[g * 10 + k] = s;
}

extern "C" void kernel_launch(void* const* d_in, const int* in_sizes, int n_in,
                              void* d_out, int out_size, void* d_ws, size_t ws_size,
                              hipStream_t stream) {
  const float* x = (const float*)d_in[0];
  const int* edge_index = (const int*)d_in[1];
  const int* batch = (const int*)d_in[2];
  const float* fc0_w = (const float*)d_in[3];
  const float* fc0_b = (const float*)d_in[4];
  const float* u1 = (const float*)d_in[5];
  const float* c1 = (const float*)d_in[6];
  const float* w1 = (const float*)d_in[7];
  const float* b1 = (const float*)d_in[8];
  const float* u2 = (const float*)d_in[9];
  const float* c2 = (const float*)d_in[10];
  const float* w2 = (const float*)d_in[11];
  const float* b2 = (const float*)d_in[12];
  const float* fc1_w = (const float*)d_in[13];
  const float* fc1_b = (const float*)d_in[14];
  float* out = (float*)d_out;

  const int* src = edge_index;            // x_j
  const int* dst = edge_index + N_EDGES;  // x_i

  // ---- workspace layout (4-byte words) ----
  // zero region: deg(N) @0, gctr @50000, pad, gsum @50004 (512), gcnt @50516 (8) -> 50524
  char* wsb = (char*)d_ws;
  int* deg = (int*)wsb;                          // N
  int* gctr = deg + N_NODES;                     // 1
  float* gsum = (float*)wsb + 50004;             // 512
  float* gcnt = gsum + NUM_GRAPHS * 64;          // 8
  int* rowstart = (int*)wsb + 50524;             // N   [50524,100524)
  int* off = rowstart + N_NODES;                 // E   [100524,900524)
  int* src_perm = off + N_EDGES;                 // E   [900524,1700524)
  float* h0 = (float*)wsb + 1700524;             // N*16
  float* h1 = h0 + (size_t)N_NODES * 16;         // N*32
  float* h2 = h1 + (size_t)N_NODES * 32;         // N*64
  float* A = h2 + (size_t)N_NODES * 64;          // N*128
  float* P1 = A + (size_t)N_NODES * 128;         // N*4
  float* P2 = P1 + (size_t)N_NODES * 4;          // N*4

  hipMemsetAsync(d_ws, 0, 50524 * sizeof(int), stream);

  int nblk = NBLK;
  int eblk = EBLK;
  int wblk = (N_NODES + 3) / 4;  // wave-per-node kernels, 4 waves/block

  // hist + fc0/P1 (independent; one grid)
  hist_fc0_kernel<<<eblk + nblk, 256, 0, stream>>>(dst, deg, off, x, fc0_w, fc0_b, u1, h0, P1);
  alloc_kernel<<<nblk, 256, 0, stream>>>(deg, gctr, rowstart);
  scatter_kernel<<<eblk, 256, 0, stream>>>(src, dst, rowstart, off, src_perm);

  // FeaStConv 1: agg (inline q) -> GEMM (+ fused P2 projection)
  agg1_kernel<<<wblk, 256, 0, stream>>>(rowstart, deg, src_perm, P1, c1, h0, A);
  gemm1_kernel<<<(N_NODES + 63) / 64, 256, 0, stream>>>(deg, A, w1, b1, u2, h1, P2);

  // FeaStConv 2
  agg2_kernel<<<wblk, 256, 0, stream>>>(rowstart, deg, src_perm, P2, c2, h1, A);
  gemm2_kernel<<<(N_NODES + 31) / 32, 256, 0, stream>>>(deg, A, w2, b2, h2);

  // Pool + head
  int pblk = (N_NODES + POOL_CHUNK * 4 - 1) / (POOL_CHUNK * 4);
  pool_kernel<<<pblk, 256, 0, stream>>>(h2, batch, gsum, gcnt);
  head_kernel<<<1, 128, 0, stream>>>(gsum, gcnt, fc1_w, fc1_b, out);
}